// Round 5
// baseline (94296.295 us; speedup 1.0000x reference)
//
#include <hip/hip_runtime.h>
#include <cstdint>
#include <cstddef>

// ---------- small helpers ----------
typedef __bf16 bf16x8 __attribute__((ext_vector_type(8)));
typedef float  f32x4  __attribute__((ext_vector_type(4)));
typedef _Float16 half8 __attribute__((ext_vector_type(8)));

__device__ __forceinline__ float b2f(unsigned short u) {
    union { uint32_t i; float f; } x; x.i = ((uint32_t)u) << 16; return x.f;
}
__device__ __forceinline__ unsigned short f2bf(float f) {
    uint32_t u = __float_as_uint(f);
    uint32_t r = (u + 0x7FFFu + ((u >> 16) & 1u)) >> 16;   // RNE, no NaN in data
    return (unsigned short)r;
}

// JAX threefry2x32 (20 rounds), usable host+device
__host__ __device__ inline void tf2x32(uint32_t k0, uint32_t k1,
                                       uint32_t x0, uint32_t x1,
                                       uint32_t& o0, uint32_t& o1) {
    uint32_t ks2 = k0 ^ k1 ^ 0x1BD11BDAu;
#define TF_ROT(x,n) (((x) << (n)) | ((x) >> (32 - (n))))
#define TF_RND(r) { x0 += x1; x1 = TF_ROT(x1, r); x1 ^= x0; }
    x0 += k0; x1 += k1;
    TF_RND(13) TF_RND(15) TF_RND(26) TF_RND(6)
    x0 += k1; x1 += ks2 + 1u;
    TF_RND(17) TF_RND(29) TF_RND(16) TF_RND(24)
    x0 += ks2; x1 += k0 + 2u;
    TF_RND(13) TF_RND(15) TF_RND(26) TF_RND(6)
    x0 += k0; x1 += k1 + 3u;
    TF_RND(17) TF_RND(29) TF_RND(16) TF_RND(24)
    x0 += k1; x1 += ks2 + 4u;
    TF_RND(13) TF_RND(15) TF_RND(26) TF_RND(6)
    x0 += ks2; x1 += k0 + 5u;
    o0 = x0; o1 = x1;
#undef TF_RND
#undef TF_ROT
}

// ---------- constants ----------
#define BATCH 32
#define TSAMP 524288
#define FRAMES 1024
#define HID 256
#define GATES 1024            // 4*HID
#define MROWS 32768           // BATCH*FRAMES
#define NCLS 29
#define NMASK 16777216u       // 32*1024*512
#define TCH 256               // time chunk
#define NCHUNK 4

// ---------- stats: per-batch mean / 1/(std+eps) ----------
__global__ __launch_bounds__(256) void k_stats1(const float* __restrict__ sig,
                                                float* __restrict__ psum,
                                                float* __restrict__ psq) {
    int blk = blockIdx.x;               // 1024 blocks, 32 per batch
    int tid = threadIdx.x;
    size_t base = (size_t)blk * 16384;
    float s = 0.f, q = 0.f;
    for (int i = 0; i < 16; ++i) {
        float4 v = *reinterpret_cast<const float4*>(sig + base + ((size_t)i * 256 + tid) * 4);
        s += v.x + v.y + v.z + v.w;
        q += v.x * v.x + v.y * v.y + v.z * v.z + v.w * v.w;
    }
    __shared__ float ls[4], lq[4];
    int w = tid >> 6, lane = tid & 63;
    for (int m = 32; m; m >>= 1) { s += __shfl_down(s, m); q += __shfl_down(q, m); }
    if (lane == 0) { ls[w] = s; lq[w] = q; }
    __syncthreads();
    if (tid == 0) {
        psum[blk] = ls[0] + ls[1] + ls[2] + ls[3];
        psq[blk]  = lq[0] + lq[1] + lq[2] + lq[3];
    }
}

__global__ __launch_bounds__(1024) void k_stats2(const float* __restrict__ psum,
                                                 const float* __restrict__ psq,
                                                 float* __restrict__ mu,
                                                 float* __restrict__ rstd) {
    int tid = threadIdx.x;              // 1024 = 32 batches * 32 chunks
    float s = psum[tid], q = psq[tid];
    for (int m = 16; m; m >>= 1) { s += __shfl_down(s, m); q += __shfl_down(q, m); }
    if ((tid & 31) == 0) {
        int b = tid >> 5;
        float m_ = s * (1.f / (float)TSAMP);
        float v  = q * (1.f / (float)TSAMP) - m_ * m_;
        float sd = sqrtf(fmaxf(v, 0.f));
        mu[b] = m_;
        rstd[b] = 1.f / (sd + 1e-8f);
    }
}

// ---------- normalize + frame -> bf16 hi/lo pair [32768][512] ----------
__global__ __launch_bounds__(256) void k_norm(const float* __restrict__ sig,
                                              const float* __restrict__ mu,
                                              const float* __restrict__ rstd,
                                              unsigned short* __restrict__ xh,
                                              unsigned short* __restrict__ xl) {
    size_t gid = (size_t)blockIdx.x * 256 + threadIdx.x;   // 4194304 threads, 4 elems each
    int b = (int)(gid >> 17);
    float m = mu[b], r = rstd[b];
    float4 v = *reinterpret_cast<const float4*>(sig + gid * 4);
    float f0 = (v.x - m) * r, f1 = (v.y - m) * r, f2 = (v.z - m) * r, f3 = (v.w - m) * r;
    ushort4 oh, ol;
    oh.x = f2bf(f0); ol.x = f2bf(f0 - b2f(oh.x));
    oh.y = f2bf(f1); ol.y = f2bf(f1 - b2f(oh.y));
    oh.z = f2bf(f2); ol.z = f2bf(f2 - b2f(oh.z));
    oh.w = f2bf(f3); ol.w = f2bf(f3 - b2f(oh.w));
    *reinterpret_cast<ushort4*>(xh + gid * 4) = oh;
    *reinterpret_cast<ushort4*>(xl + gid * 4) = ol;
}

// ---------- weight prep: Wih transpose + hi/lo split ----------
__global__ __launch_bounds__(256) void k_wih_t(const float* __restrict__ Wih,
                                               unsigned short* __restrict__ WTh,
                                               unsigned short* __restrict__ WTl) {
    size_t gid = (size_t)blockIdx.x * 256 + threadIdx.x;   // 3145728
    int k = (int)(gid & 511);
    int n = (int)((gid >> 9) & 1023);
    int ld = (int)(gid >> 19);
    float w = Wih[((size_t)ld * 512 + k) * 1024 + n];
    unsigned short h = f2bf(w);
    WTh[gid] = h;
    WTl[gid] = f2bf(w - b2f(h));
}

// ---------- weight prep: Whh -> fp16, transposed to [ld][col][k] ----------
__global__ __launch_bounds__(256) void k_whh16(const float* __restrict__ W,
                                               _Float16* __restrict__ WT) {
    size_t gid = (size_t)blockIdx.x * 256 + threadIdx.x;   // 1572864
    int k = (int)(gid & 255);
    int col = (int)((gid >> 8) & 1023);
    int ld = (int)(gid >> 18);
    WT[gid] = (_Float16)W[((size_t)ld * 256 + k) * 1024 + col];
}

// ---------- zero the sync flags (before every scan dispatch) ----------
__global__ __launch_bounds__(256) void k_zero(uint32_t* __restrict__ p) {
    p[blockIdx.x * 256u + threadIdx.x] = 0u;   // grid 64 -> 16384 uints
}

// ---------- chunked input GEMM (split-bf16 MFMA, fp32 out) ----------
__global__ __launch_bounds__(256) void k_gemm_chunk(const unsigned short* __restrict__ Ah,
                                                    const unsigned short* __restrict__ Al,
                                                    const unsigned short* __restrict__ BTh,
                                                    const unsigned short* __restrict__ BTl,
                                                    float* __restrict__ C,
                                                    int t0) {
    __shared__ __align__(16) unsigned short Ahs[128][40];
    __shared__ __align__(16) unsigned short Als[128][40];
    __shared__ __align__(16) unsigned short Bhs[128][40];
    __shared__ __align__(16) unsigned short Bls[128][40];
    const int tid = threadIdx.x;
    const int tm = blockIdx.y * 128;     // gridDim.y = 64  (8192 chunk rows)
    const int tn = blockIdx.x * 128;     // gridDim.x = 8   (1024 gate cols)
    const int lane = tid & 63, w = tid >> 6;
    const int wr = w >> 1, wc = w & 1;
    const int l15 = lane & 15, lk = (lane >> 4) * 8;
    f32x4 acc[4][4];
    for (int i = 0; i < 4; ++i)
        for (int j = 0; j < 4; ++j)
            acc[i][j] = (f32x4){0.f, 0.f, 0.f, 0.f};
    const int srow = tid >> 1, scol = (tid & 1) * 16;
    const int rg = tm + srow;
    const size_t am = (size_t)((rg >> 8) * 1024 + t0 + (rg & 255)) * 512;
    const size_t bm = (size_t)(tn + srow) * 512;
    for (int kt = 0; kt < 512; kt += 32) {
        *reinterpret_cast<uint4*>(&Ahs[srow][scol])     = *reinterpret_cast<const uint4*>(&Ah[am + kt + scol]);
        *reinterpret_cast<uint4*>(&Ahs[srow][scol + 8]) = *reinterpret_cast<const uint4*>(&Ah[am + kt + scol + 8]);
        *reinterpret_cast<uint4*>(&Als[srow][scol])     = *reinterpret_cast<const uint4*>(&Al[am + kt + scol]);
        *reinterpret_cast<uint4*>(&Als[srow][scol + 8]) = *reinterpret_cast<const uint4*>(&Al[am + kt + scol + 8]);
        *reinterpret_cast<uint4*>(&Bhs[srow][scol])     = *reinterpret_cast<const uint4*>(&BTh[bm + kt + scol]);
        *reinterpret_cast<uint4*>(&Bhs[srow][scol + 8]) = *reinterpret_cast<const uint4*>(&BTh[bm + kt + scol + 8]);
        *reinterpret_cast<uint4*>(&Bls[srow][scol])     = *reinterpret_cast<const uint4*>(&BTl[bm + kt + scol]);
        *reinterpret_cast<uint4*>(&Bls[srow][scol + 8]) = *reinterpret_cast<const uint4*>(&BTl[bm + kt + scol + 8]);
        __syncthreads();
        bf16x8 afh[4], afl[4], bfh[4], bfl[4];
        for (int m = 0; m < 4; ++m) {
            afh[m] = *reinterpret_cast<const bf16x8*>(&Ahs[wr * 64 + m * 16 + l15][lk]);
            afl[m] = *reinterpret_cast<const bf16x8*>(&Als[wr * 64 + m * 16 + l15][lk]);
        }
        for (int n = 0; n < 4; ++n) {
            bfh[n] = *reinterpret_cast<const bf16x8*>(&Bhs[wc * 64 + n * 16 + l15][lk]);
            bfl[n] = *reinterpret_cast<const bf16x8*>(&Bls[wc * 64 + n * 16 + l15][lk]);
        }
        for (int m = 0; m < 4; ++m)
            for (int n = 0; n < 4; ++n) {
                acc[m][n] = __builtin_amdgcn_mfma_f32_16x16x32_bf16(afh[m], bfh[n], acc[m][n], 0, 0, 0);
                acc[m][n] = __builtin_amdgcn_mfma_f32_16x16x32_bf16(afl[m], bfh[n], acc[m][n], 0, 0, 0);
                acc[m][n] = __builtin_amdgcn_mfma_f32_16x16x32_bf16(afh[m], bfl[n], acc[m][n], 0, 0, 0);
            }
        __syncthreads();
    }
    const int rbase = tm + wr * 64 + (lane >> 4) * 4;
    const int cbase = tn + wc * 64 + l15;
    for (int m = 0; m < 4; ++m)
        for (int n = 0; n < 4; ++n)
            for (int r = 0; r < 4; ++r) {
                int row = rbase + m * 16 + r;
                int col = cbase + n * 16;
                C[(size_t)row * 1024 + col] = acc[m][n][r];
            }
}

// ---------- LSTM scan, 4-way split, LDS-resident fp16 Whh ----------
// Grid 256 blocks x 256 threads. block: group g = bid&63 (d=g>>5, b=g&31), quarter q=bid>>6.
// Block owns units [q*64, q*64+64); its 256 gate columns = {gate*256 + q*64 + u}.
// LDS ~138 KB -> exactly 1 block/CU -> all 256 blocks co-resident (spin-safe).
// Peers {g, g+64, g+128, g+192} land on one XCD under round-robin dispatch (perf only).
// Per-step protocol: compute gates from LDS W + LDS h -> own h slice ->
// publish via device-scope atomics -> flag release -> acquire-spin -> gather peers.
__global__ __launch_bounds__(256) void k_scan2(const _Float16* __restrict__ WT16,  // [ld][1024 col][256 k]
                                               const float* __restrict__ bias,
                                               const float* __restrict__ xgA,      // fwd [32][256][1024]
                                               const float* __restrict__ xgB,      // bwd [32][256][1024]
                                               float* __restrict__ hout,
                                               float* __restrict__ hstate,         // [64][256]
                                               float* __restrict__ cstate,         // [64][256]
                                               float* __restrict__ hx,             // [64][2][256]
                                               uint32_t* __restrict__ flags,       // [64][256]
                                               int layer, int chunk) {
    const int bid = blockIdx.x;
    const int g = bid & 63;
    const int q = bid >> 6;
    const int d = g >> 5, b = g & 31;
    const int tid = threadIdx.x;                 // 0..255
    const int gate = tid >> 6, ul = tid & 63;    // gate == wave index (no divergence)
    const int colg = gate * 256 + q * 64 + ul;   // global gate column
    const int ld = layer * 2 + d;

    __shared__ __align__(16) _Float16 Wl[256][264];   // 264 = 256 + 16B pad
    __shared__ __align__(16) float h_lds[256];
    __shared__ float gbuf[4][64];
    __shared__ float blds[256];

    // stage fp16 weight slice: local col = tid, global col = colg
    {
        const _Float16* src = WT16 + ((size_t)ld * 1024 + colg) * 256;
        #pragma unroll
        for (int kc = 0; kc < 256; kc += 8)
            *reinterpret_cast<half8*>(&Wl[tid][kc]) = *reinterpret_cast<const half8*>(src + kc);
        blds[tid] = bias[(size_t)ld * 1024 + colg];
    }
    float c = 0.f;
    if (chunk == 0) {
        h_lds[tid < 256 ? tid : 0] = 0.f;
    } else {
        h_lds[tid] = hstate[(size_t)g * 256 + tid];
        if (tid < 64) c = cstate[(size_t)g * 256 + q * 64 + tid];
    }
    __syncthreads();

    const float* xbase = (d ? xgB : xgA) + (size_t)b * TCH * 1024 + colg;
    uint32_t* flg = flags + g * TCH;
    float* hxg = hx + (size_t)g * 512;           // [2][256]

    const int tl0 = d ? (TCH - 1) : 0, tstep = d ? -1 : 1;
    float xg_cur = xbase[(size_t)tl0 * 1024];

    for (int sl = 0; sl < TCH; ++sl) {
        // prefetch next xg (independent of h)
        float xg_next = xg_cur;
        if (sl + 1 < TCH)
            xg_next = xbase[(size_t)(tl0 + tstep * (sl + 1)) * 1024];

        // dot: 4 accumulators to break the serial FMA chain (1 wave/SIMD here)
        float a0 = 0.f, a1 = 0.f, a2 = 0.f, a3 = 0.f;
        #pragma unroll
        for (int kc = 0; kc < 256; kc += 8) {
            float4 h0 = *reinterpret_cast<const float4*>(&h_lds[kc]);
            float4 h1 = *reinterpret_cast<const float4*>(&h_lds[kc + 4]);
            half8 w = *reinterpret_cast<const half8*>(&Wl[tid][kc]);
            a0 += h0.x * (float)w[0] + h1.x * (float)w[4];
            a1 += h0.y * (float)w[1] + h1.y * (float)w[5];
            a2 += h0.z * (float)w[2] + h1.z * (float)w[6];
            a3 += h0.w * (float)w[3] + h1.w * (float)w[7];
        }
        float gv = (a0 + a1) + (a2 + a3) + blds[tid] + xg_cur;
        // per-gate nonlinearity, wave-uniform (gate == wave)
        gbuf[gate][ul] = (gate == 2) ? tanhf(gv) : 1.f / (1.f + expf(-gv));
        __syncthreads();

        const int sgl = chunk * TCH + sl;
        const int tg = d ? (FRAMES - 1 - sgl) : sgl;
        const int par = sl & 1;
        if (tid < 64) {
            float si = gbuf[0][tid], sf = gbuf[1][tid], gg = gbuf[2][tid], so = gbuf[3][tid];
            c = sf * c + si * gg;
            float h = so * tanhf(c);
            hout[((size_t)(d * BATCH + b) * FRAMES + tg) * HID + q * 64 + tid] = h;
            __hip_atomic_store(&hxg[par * 256 + q * 64 + tid], h,
                               __ATOMIC_RELAXED, __HIP_MEMORY_SCOPE_AGENT);
            h_lds[q * 64 + tid] = h;
        }
        __threadfence();
        __syncthreads();
        if (tid == 0)
            __hip_atomic_fetch_add(&flg[sl], 1u, __ATOMIC_RELEASE, __HIP_MEMORY_SCOPE_AGENT);
        while (__hip_atomic_load(&flg[sl], __ATOMIC_ACQUIRE, __HIP_MEMORY_SCOPE_AGENT) < 4u)
            __builtin_amdgcn_s_sleep(1);
        if (tid < 192) {
            int idx = tid + ((tid >= q * 64) ? 64 : 0);   // skip own quarter
            h_lds[idx] = __hip_atomic_load(&hxg[par * 256 + idx],
                                           __ATOMIC_RELAXED, __HIP_MEMORY_SCOPE_AGENT);
        }
        __syncthreads();
        xg_cur = xg_next;
    }
    if (tid < 64) {
        hstate[(size_t)g * 256 + q * 64 + tid] = h_lds[q * 64 + tid];
        cstate[(size_t)g * 256 + q * 64 + tid] = c;
    }
}

// ---------- dropout(0.5) + ReLU + concat, JAX partitionable threefry ----------
__global__ __launch_bounds__(256) void k_dropout(const float* __restrict__ h,
                                                 unsigned short* __restrict__ xh,  // may be null
                                                 unsigned short* __restrict__ xl,  // may be null
                                                 float* __restrict__ xf,           // may be null
                                                 uint32_t fk0, uint32_t fk1) {
    uint32_t i = blockIdx.x * 256u + threadIdx.x;    // grid 65536 -> NMASK threads
    uint32_t o0, o1;
    tf2x32(fk0, fk1, 0u, i, o0, o1);
    uint32_t bits = o0 ^ o1;
    uint32_t f = i & 511u;
    uint32_t t = (i >> 9) & 1023u;
    uint32_t b = i >> 19;                            // 0..31
    uint32_t dv = f >> 8, n = f & 255u;
    float v = h[(((size_t)dv * BATCH + b) * FRAMES + t) * HID + n];
    float o = (((bits >> 31) == 0u) && v > 0.f) ? 2.f * v : 0.f;
    if (xh != nullptr) {
        unsigned short hb_ = f2bf(o);
        xh[i] = hb_;
        xl[i] = f2bf(o - b2f(hb_));
    }
    if (xf != nullptr) xf[i] = o;
}

// ---------- output projection: out[32768][29] = Xf[32768][512] @ Wout + bout ----------
__global__ __launch_bounds__(256) void k_out(const float* __restrict__ xf,
                                             const float* __restrict__ Wout,
                                             const float* __restrict__ bout,
                                             float* __restrict__ out) {
    __shared__ __align__(16) float Xs[64][68];
    const int tid = threadIdx.x;
    const int r = tid & 63, cg = tid >> 6;           // 4 col-groups of 8 (last has 5)
    const int row0 = blockIdx.x * 64;
    float acc[8] = {0.f, 0.f, 0.f, 0.f, 0.f, 0.f, 0.f, 0.f};
    for (int kc = 0; kc < 512; kc += 64) {
        int sr = tid >> 2, sc = (tid & 3) * 16;
        const float* src = xf + (size_t)(row0 + sr) * 512 + kc + sc;
        *reinterpret_cast<float4*>(&Xs[sr][sc])      = *reinterpret_cast<const float4*>(src);
        *reinterpret_cast<float4*>(&Xs[sr][sc + 4])  = *reinterpret_cast<const float4*>(src + 4);
        *reinterpret_cast<float4*>(&Xs[sr][sc + 8])  = *reinterpret_cast<const float4*>(src + 8);
        *reinterpret_cast<float4*>(&Xs[sr][sc + 12]) = *reinterpret_cast<const float4*>(src + 12);
        __syncthreads();
        for (int k = 0; k < 64; ++k) {
            float xv = Xs[r][k];
            const float* wr = Wout + (size_t)(kc + k) * NCLS + cg * 8;
            #pragma unroll
            for (int cc = 0; cc < 8; ++cc)
                if (cg * 8 + cc < NCLS) acc[cc] = fmaf(xv, wr[cc], acc[cc]);
        }
        __syncthreads();
    }
    for (int cc = 0; cc < 8; ++cc) {
        int col = cg * 8 + cc;
        if (col < NCLS) out[(size_t)(row0 + r) * NCLS + col] = acc[cc] + bout[col];
    }
}

// ---------- launch ----------
extern "C" void kernel_launch(void* const* d_in, const int* in_sizes, int n_in,
                              void* d_out, int out_size, void* d_ws, size_t ws_size,
                              hipStream_t stream) {
    const float* sig  = (const float*)d_in[0];
    const float* Wih  = (const float*)d_in[1];
    const float* Whh  = (const float*)d_in[2];
    const float* bias = (const float*)d_in[3];
    const float* Wout = (const float*)d_in[4];
    const float* bout = (const float*)d_in[5];
    float* out = (float*)d_out;

    char* ws = (char*)d_ws;
    size_t off = 0;
    auto alloc = [&](size_t bytes) -> void* {
        void* p = ws + off;
        off += (bytes + 255) & ~(size_t)255;
        return p;
    };
    float* psum           = (float*)alloc(1024 * 4);
    float* psq            = (float*)alloc(1024 * 4);
    float* mu             = (float*)alloc(32 * 4);
    float* rstd           = (float*)alloc(32 * 4);
    unsigned short* WThi  = (unsigned short*)alloc((size_t)6 * 1024 * 512 * 2);     // 6.3 MB
    unsigned short* WTlo  = (unsigned short*)alloc((size_t)6 * 1024 * 512 * 2);     // 6.3 MB
    _Float16* WT16        = (_Float16*)alloc((size_t)6 * 1024 * 256 * 2);           // 3.1 MB
    unsigned short* xhi   = (unsigned short*)alloc((size_t)MROWS * 512 * 2);        // 33.5 MB
    unsigned short* xlo   = (unsigned short*)alloc((size_t)MROWS * 512 * 2);        // 33.5 MB
    float* xgA            = (float*)alloc((size_t)BATCH * TCH * 1024 * 4);          // 33.5 MB
    float* xgB            = (float*)alloc((size_t)BATCH * TCH * 1024 * 4);          // 33.5 MB
    float* hb             = (float*)alloc((size_t)2 * BATCH * FRAMES * HID * 4);    // 67 MB
    float* hstate         = (float*)alloc((size_t)64 * HID * 4);
    float* cstate         = (float*)alloc((size_t)64 * HID * 4);
    float* hx             = (float*)alloc((size_t)64 * 2 * HID * 4);                // 128 KB
    uint32_t* flags       = (uint32_t*)alloc((size_t)64 * TCH * 4);                 // 64 KB
    // Total ~218 MB (round-4's 214 MB layout + 3.3 MB; round-1's 244 MB ran fine).
    float* xf32           = (float*)xhi;   // layer-2 fp32 activations overlay dead xhi/xlo

    k_stats1<<<1024, 256, 0, stream>>>(sig, psum, psq);
    k_stats2<<<1, 1024, 0, stream>>>(psum, psq, mu, rstd);
    k_norm<<<16384, 256, 0, stream>>>(sig, mu, rstd, xhi, xlo);
    k_wih_t<<<12288, 256, 0, stream>>>(Wih, WThi, WTlo);
    k_whh16<<<6144, 256, 0, stream>>>(Whh, WT16);

    for (int l = 0; l < 3; ++l) {
        const unsigned short* Bh0 = WThi + (size_t)(l * 2 + 0) * 1024 * 512;
        const unsigned short* Bl0 = WTlo + (size_t)(l * 2 + 0) * 1024 * 512;
        const unsigned short* Bh1 = WThi + (size_t)(l * 2 + 1) * 1024 * 512;
        const unsigned short* Bl1 = WTlo + (size_t)(l * 2 + 1) * 1024 * 512;
        for (int c = 0; c < NCHUNK; ++c) {
            dim3 gg(8, 64);
            int t0f = c * TCH;
            int t0b = (NCHUNK - 1 - c) * TCH;
            k_gemm_chunk<<<gg, 256, 0, stream>>>(xhi, xlo, Bh0, Bl0, xgA, t0f);
            k_gemm_chunk<<<gg, 256, 0, stream>>>(xhi, xlo, Bh1, Bl1, xgB, t0b);
            k_zero<<<64, 256, 0, stream>>>(flags);
            k_scan2<<<256, 256, 0, stream>>>(WT16, bias, xgA, xgB, hb, hstate, cstate,
                                             hx, flags, l, c);
        }
        uint32_t fk0, fk1;
        tf2x32(0u, 42u, 0u, (uint32_t)l, fk0, fk1);
        if (l < 2)
            k_dropout<<<65536, 256, 0, stream>>>(hb, xhi, xlo, nullptr, fk0, fk1);
        else
            k_dropout<<<65536, 256, 0, stream>>>(hb, nullptr, nullptr, xf32, fk0, fk1);
    }
    k_out<<<512, 256, 0, stream>>>(xf32, Wout, bout, out);
}

// Round 6
// 63028.546 us; speedup vs baseline: 1.4961x; 1.4961x over previous
//
#include <hip/hip_runtime.h>
#include <cstdint>
#include <cstddef>

// ---------- small helpers ----------
typedef __bf16 bf16x8 __attribute__((ext_vector_type(8)));
typedef float  f32x4  __attribute__((ext_vector_type(4)));
typedef _Float16 h2 __attribute__((ext_vector_type(2)));

__device__ __forceinline__ float b2f(unsigned short u) {
    union { uint32_t i; float f; } x; x.i = ((uint32_t)u) << 16; return x.f;
}
__device__ __forceinline__ unsigned short f2bf(float f) {
    uint32_t u = __float_as_uint(f);
    uint32_t r = (u + 0x7FFFu + ((u >> 16) & 1u)) >> 16;   // RNE, no NaN in data
    return (unsigned short)r;
}
__device__ __forceinline__ uint32_t packf16(float a, float b) {
    union { _Float16 h[2]; uint32_t u; } x;
    x.h[0] = (_Float16)a; x.h[1] = (_Float16)b; return x.u;
}
__device__ __forceinline__ h2 u2h(uint32_t u) {
    union { uint32_t u; h2 v; } x; x.u = u; return x.v;
}
__device__ __forceinline__ unsigned short f16b(float f) {
    union { _Float16 h; unsigned short u; } x; x.h = (_Float16)f; return x.u;
}

#if __has_builtin(__builtin_amdgcn_fdot2)
#define FDOT2(w, hh, acc) __builtin_amdgcn_fdot2((w), (hh), (acc), false)
#else
__device__ __forceinline__ float fdot2_sw(h2 a, h2 b, float c) {
    return c + (float)a[0] * (float)b[0] + (float)a[1] * (float)b[1];
}
#define FDOT2(w, hh, acc) fdot2_sw((w), (hh), (acc))
#endif

// JAX threefry2x32 (20 rounds), usable host+device
__host__ __device__ inline void tf2x32(uint32_t k0, uint32_t k1,
                                       uint32_t x0, uint32_t x1,
                                       uint32_t& o0, uint32_t& o1) {
    uint32_t ks2 = k0 ^ k1 ^ 0x1BD11BDAu;
#define TF_ROT(x,n) (((x) << (n)) | ((x) >> (32 - (n))))
#define TF_RND(r) { x0 += x1; x1 = TF_ROT(x1, r); x1 ^= x0; }
    x0 += k0; x1 += k1;
    TF_RND(13) TF_RND(15) TF_RND(26) TF_RND(6)
    x0 += k1; x1 += ks2 + 1u;
    TF_RND(17) TF_RND(29) TF_RND(16) TF_RND(24)
    x0 += ks2; x1 += k0 + 2u;
    TF_RND(13) TF_RND(15) TF_RND(26) TF_RND(6)
    x0 += k0; x1 += k1 + 3u;
    TF_RND(17) TF_RND(29) TF_RND(16) TF_RND(24)
    x0 += k1; x1 += ks2 + 4u;
    TF_RND(13) TF_RND(15) TF_RND(26) TF_RND(6)
    x0 += ks2; x1 += k0 + 5u;
    o0 = x0; o1 = x1;
#undef TF_RND
#undef TF_ROT
}

// ---------- constants ----------
#define BATCH 32
#define TSAMP 524288
#define FRAMES 1024
#define HID 256
#define GATES 1024            // 4*HID
#define MROWS 32768           // BATCH*FRAMES
#define NCLS 29
#define NMASK 16777216u       // 32*1024*512
#define TCH 256               // time chunk
#define NCHUNK 4

// ---------- stats: per-batch mean / 1/(std+eps) ----------
__global__ __launch_bounds__(256) void k_stats1(const float* __restrict__ sig,
                                                float* __restrict__ psum,
                                                float* __restrict__ psq) {
    int blk = blockIdx.x;               // 1024 blocks, 32 per batch
    int tid = threadIdx.x;
    size_t base = (size_t)blk * 16384;
    float s = 0.f, q = 0.f;
    for (int i = 0; i < 16; ++i) {
        float4 v = *reinterpret_cast<const float4*>(sig + base + ((size_t)i * 256 + tid) * 4);
        s += v.x + v.y + v.z + v.w;
        q += v.x * v.x + v.y * v.y + v.z * v.z + v.w * v.w;
    }
    __shared__ float ls[4], lq[4];
    int w = tid >> 6, lane = tid & 63;
    for (int m = 32; m; m >>= 1) { s += __shfl_down(s, m); q += __shfl_down(q, m); }
    if (lane == 0) { ls[w] = s; lq[w] = q; }
    __syncthreads();
    if (tid == 0) {
        psum[blk] = ls[0] + ls[1] + ls[2] + ls[3];
        psq[blk]  = lq[0] + lq[1] + lq[2] + lq[3];
    }
}

__global__ __launch_bounds__(1024) void k_stats2(const float* __restrict__ psum,
                                                 const float* __restrict__ psq,
                                                 float* __restrict__ mu,
                                                 float* __restrict__ rstd) {
    int tid = threadIdx.x;              // 1024 = 32 batches * 32 chunks
    float s = psum[tid], q = psq[tid];
    for (int m = 16; m; m >>= 1) { s += __shfl_down(s, m); q += __shfl_down(q, m); }
    if ((tid & 31) == 0) {
        int b = tid >> 5;
        float m_ = s * (1.f / (float)TSAMP);
        float v  = q * (1.f / (float)TSAMP) - m_ * m_;
        float sd = sqrtf(fmaxf(v, 0.f));
        mu[b] = m_;
        rstd[b] = 1.f / (sd + 1e-8f);
    }
}

// ---------- normalize + frame -> bf16 hi/lo pair [32768][512] ----------
__global__ __launch_bounds__(256) void k_norm(const float* __restrict__ sig,
                                              const float* __restrict__ mu,
                                              const float* __restrict__ rstd,
                                              unsigned short* __restrict__ xh,
                                              unsigned short* __restrict__ xl) {
    size_t gid = (size_t)blockIdx.x * 256 + threadIdx.x;   // 4194304 threads, 4 elems each
    int b = (int)(gid >> 17);
    float m = mu[b], r = rstd[b];
    float4 v = *reinterpret_cast<const float4*>(sig + gid * 4);
    float f0 = (v.x - m) * r, f1 = (v.y - m) * r, f2 = (v.z - m) * r, f3 = (v.w - m) * r;
    ushort4 oh, ol;
    oh.x = f2bf(f0); ol.x = f2bf(f0 - b2f(oh.x));
    oh.y = f2bf(f1); ol.y = f2bf(f1 - b2f(oh.y));
    oh.z = f2bf(f2); ol.z = f2bf(f2 - b2f(oh.z));
    oh.w = f2bf(f3); ol.w = f2bf(f3 - b2f(oh.w));
    *reinterpret_cast<ushort4*>(xh + gid * 4) = oh;
    *reinterpret_cast<ushort4*>(xl + gid * 4) = ol;
}

// ---------- weight prep: Wih transpose + hi/lo split ----------
__global__ __launch_bounds__(256) void k_wih_t(const float* __restrict__ Wih,
                                               unsigned short* __restrict__ WTh,
                                               unsigned short* __restrict__ WTl) {
    size_t gid = (size_t)blockIdx.x * 256 + threadIdx.x;   // 3145728
    int k = (int)(gid & 511);
    int n = (int)((gid >> 9) & 1023);
    int ld = (int)(gid >> 19);
    float w = Wih[((size_t)ld * 512 + k) * 1024 + n];
    unsigned short h = f2bf(w);
    WTh[gid] = h;
    WTl[gid] = f2bf(w - b2f(h));
}

// ---------- weight prep: Whh -> packed fp16 pairs, layout [ld][kpair=128][col=1024] ----------
__global__ __launch_bounds__(256) void k_wkm(const float* __restrict__ W,
                                             uint32_t* __restrict__ Wkm) {
    size_t gid = (size_t)blockIdx.x * 256 + threadIdx.x;   // 786432
    int col = (int)(gid & 1023);
    int kk  = (int)((gid >> 10) & 127);
    int ld  = (int)(gid >> 17);
    float w0 = W[((size_t)ld * 256 + 2 * kk) * 1024 + col];
    float w1 = W[((size_t)ld * 256 + 2 * kk + 1) * 1024 + col];
    Wkm[gid] = packf16(w0, w1);
}

// ---------- chunked input GEMM (split-bf16 MFMA, fp32 out) ----------
__global__ __launch_bounds__(256) void k_gemm_chunk(const unsigned short* __restrict__ Ah,
                                                    const unsigned short* __restrict__ Al,
                                                    const unsigned short* __restrict__ BTh,
                                                    const unsigned short* __restrict__ BTl,
                                                    float* __restrict__ C,
                                                    int t0) {
    __shared__ __align__(16) unsigned short Ahs[128][40];
    __shared__ __align__(16) unsigned short Als[128][40];
    __shared__ __align__(16) unsigned short Bhs[128][40];
    __shared__ __align__(16) unsigned short Bls[128][40];
    const int tid = threadIdx.x;
    const int tm = blockIdx.y * 128;     // gridDim.y = 64  (8192 chunk rows)
    const int tn = blockIdx.x * 128;     // gridDim.x = 8   (1024 gate cols)
    const int lane = tid & 63, w = tid >> 6;
    const int wr = w >> 1, wc = w & 1;
    const int l15 = lane & 15, lk = (lane >> 4) * 8;
    f32x4 acc[4][4];
    for (int i = 0; i < 4; ++i)
        for (int j = 0; j < 4; ++j)
            acc[i][j] = (f32x4){0.f, 0.f, 0.f, 0.f};
    const int srow = tid >> 1, scol = (tid & 1) * 16;
    const int rg = tm + srow;
    const size_t am = (size_t)((rg >> 8) * 1024 + t0 + (rg & 255)) * 512;
    const size_t bm = (size_t)(tn + srow) * 512;
    for (int kt = 0; kt < 512; kt += 32) {
        *reinterpret_cast<uint4*>(&Ahs[srow][scol])     = *reinterpret_cast<const uint4*>(&Ah[am + kt + scol]);
        *reinterpret_cast<uint4*>(&Ahs[srow][scol + 8]) = *reinterpret_cast<const uint4*>(&Ah[am + kt + scol + 8]);
        *reinterpret_cast<uint4*>(&Als[srow][scol])     = *reinterpret_cast<const uint4*>(&Al[am + kt + scol]);
        *reinterpret_cast<uint4*>(&Als[srow][scol + 8]) = *reinterpret_cast<const uint4*>(&Al[am + kt + scol + 8]);
        *reinterpret_cast<uint4*>(&Bhs[srow][scol])     = *reinterpret_cast<const uint4*>(&BTh[bm + kt + scol]);
        *reinterpret_cast<uint4*>(&Bhs[srow][scol + 8]) = *reinterpret_cast<const uint4*>(&BTh[bm + kt + scol + 8]);
        *reinterpret_cast<uint4*>(&Bls[srow][scol])     = *reinterpret_cast<const uint4*>(&BTl[bm + kt + scol]);
        *reinterpret_cast<uint4*>(&Bls[srow][scol + 8]) = *reinterpret_cast<const uint4*>(&BTl[bm + kt + scol + 8]);
        __syncthreads();
        bf16x8 afh[4], afl[4], bfh[4], bfl[4];
        for (int m = 0; m < 4; ++m) {
            afh[m] = *reinterpret_cast<const bf16x8*>(&Ahs[wr * 64 + m * 16 + l15][lk]);
            afl[m] = *reinterpret_cast<const bf16x8*>(&Als[wr * 64 + m * 16 + l15][lk]);
        }
        for (int n = 0; n < 4; ++n) {
            bfh[n] = *reinterpret_cast<const bf16x8*>(&Bhs[wc * 64 + n * 16 + l15][lk]);
            bfl[n] = *reinterpret_cast<const bf16x8*>(&Bls[wc * 64 + n * 16 + l15][lk]);
        }
        for (int m = 0; m < 4; ++m)
            for (int n = 0; n < 4; ++n) {
                acc[m][n] = __builtin_amdgcn_mfma_f32_16x16x32_bf16(afh[m], bfh[n], acc[m][n], 0, 0, 0);
                acc[m][n] = __builtin_amdgcn_mfma_f32_16x16x32_bf16(afl[m], bfh[n], acc[m][n], 0, 0, 0);
                acc[m][n] = __builtin_amdgcn_mfma_f32_16x16x32_bf16(afh[m], bfl[n], acc[m][n], 0, 0, 0);
            }
        __syncthreads();
    }
    const int rbase = tm + wr * 64 + (lane >> 4) * 4;
    const int cbase = tn + wc * 64 + l15;
    for (int m = 0; m < 4; ++m)
        for (int n = 0; n < 4; ++n)
            for (int r = 0; r < 4; ++r) {
                int row = rbase + m * 16 + r;
                int col = cbase + n * 16;
                C[(size_t)row * 1024 + col] = acc[m][n][r];
            }
}

// ---------- LSTM scan: one block per (dir,batch); W on-chip ----------
// 64 blocks x 512 threads, __launch_bounds__(512,2) -> 1 block/CU, <=256 VGPR.
// Thread t owns gate columns c0 = t (in REGISTERS, 128 packed fp16 pairs)
// and c1 = 512+t (t<256: LDS-resident; t>=256: streamed from L2 each step).
// h carried as fp16 pairs in LDS; dot via v_dot2_f32_f16 (exact fp32 accum).
// No cross-block communication (round-5 lesson: per-step fabric sync ~29us/step).
__global__ __launch_bounds__(512, 2) void k_scan3(const uint32_t* __restrict__ Wkm,  // [ld][128][1024]
                                                  const float* __restrict__ bias,
                                                  const float* __restrict__ xgA,    // fwd [32][256][1024]
                                                  const float* __restrict__ xgB,    // bwd [32][256][1024]
                                                  float* __restrict__ hout,
                                                  float* __restrict__ hstate,       // [64][256]
                                                  float* __restrict__ cstate,       // [64][256]
                                                  int layer, int chunk) {
    const int g = blockIdx.x;                   // 0..63
    const int d = g >> 5, b = g & 31;
    const int tid = threadIdx.x;                // 0..511
    const int ld = layer * 2 + d;

    __shared__ __align__(16) uint32_t Wlds[128 * 256];   // cols 512..767, [kpair][col] 128 KB
    __shared__ __align__(16) float gbuf[GATES];          // 4 KB
    __shared__ __align__(16) unsigned short hh_u16[HID]; // h as fp16, 512 B

    const uint32_t* Wld = Wkm + (size_t)ld * 131072;

    // ---- stage LDS cols (512..767): coalesced both sides ----
    for (int idx = tid; idx < 128 * 256; idx += 512) {
        int kk = idx >> 8, c = idx & 255;
        Wlds[idx] = Wld[(size_t)kk * 1024 + 512 + c];
    }
    // ---- stage register cols (col = tid): 128 coalesced b32 loads ----
    uint32_t wr[128];
    {
        const uint32_t* gc = Wld + tid;
        #pragma unroll
        for (int kk = 0; kk < 128; ++kk)
            wr[kk] = gc[(size_t)kk * 1024];
    }
    const float b0 = bias[(size_t)ld * 1024 + tid];
    const float b1 = bias[(size_t)ld * 1024 + 512 + tid];

    float creg = 0.f, hreg = 0.f;
    if (tid < HID) {
        if (chunk != 0) {
            hreg = hstate[(size_t)g * 256 + tid];
            creg = cstate[(size_t)g * 256 + tid];
        }
        hh_u16[tid] = f16b(hreg);
    }
    __syncthreads();

    const float* xbase = (d ? xgB : xgA) + (size_t)b * TCH * 1024;
    const uint32_t* wst = Wld + 512 + tid;      // streamed col (only used by tid>=256)
    const uint4* hh4 = reinterpret_cast<const uint4*>(hh_u16);

    const int tl0 = d ? (TCH - 1) : 0, tstep = d ? -1 : 1;
    float xg0 = xbase[(size_t)tl0 * 1024 + tid];
    float xg1 = xbase[(size_t)tl0 * 1024 + 512 + tid];

    for (int sl = 0; sl < TCH; ++sl) {
        // prefetch next step's xg (independent of h)
        float xg0n = xg0, xg1n = xg1;
        if (sl + 1 < TCH) {
            size_t r = (size_t)(tl0 + tstep * (sl + 1)) * 1024;
            xg0n = xbase[r + tid];
            xg1n = xbase[r + 512 + tid];
        }

        float a0 = 0.f, a1 = 0.f;
        if (tid < 256) {
            #pragma unroll
            for (int bk = 0; bk < 32; ++bk) {
                uint4 hv = hh4[bk];
                a0 = FDOT2(u2h(wr[4 * bk + 0]), u2h(hv.x), a0);
                a1 = FDOT2(u2h(Wlds[(4 * bk + 0) * 256 + tid]), u2h(hv.x), a1);
                a0 = FDOT2(u2h(wr[4 * bk + 1]), u2h(hv.y), a0);
                a1 = FDOT2(u2h(Wlds[(4 * bk + 1) * 256 + tid]), u2h(hv.y), a1);
                a0 = FDOT2(u2h(wr[4 * bk + 2]), u2h(hv.z), a0);
                a1 = FDOT2(u2h(Wlds[(4 * bk + 2) * 256 + tid]), u2h(hv.z), a1);
                a0 = FDOT2(u2h(wr[4 * bk + 3]), u2h(hv.w), a0);
                a1 = FDOT2(u2h(Wlds[(4 * bk + 3) * 256 + tid]), u2h(hv.w), a1);
            }
        } else {
            #pragma unroll
            for (int bk = 0; bk < 32; ++bk) {
                uint4 hv = hh4[bk];
                a0 = FDOT2(u2h(wr[4 * bk + 0]), u2h(hv.x), a0);
                a1 = FDOT2(u2h(wst[(size_t)(4 * bk + 0) * 1024]), u2h(hv.x), a1);
                a0 = FDOT2(u2h(wr[4 * bk + 1]), u2h(hv.y), a0);
                a1 = FDOT2(u2h(wst[(size_t)(4 * bk + 1) * 1024]), u2h(hv.y), a1);
                a0 = FDOT2(u2h(wr[4 * bk + 2]), u2h(hv.z), a0);
                a1 = FDOT2(u2h(wst[(size_t)(4 * bk + 2) * 1024]), u2h(hv.z), a1);
                a0 = FDOT2(u2h(wr[4 * bk + 3]), u2h(hv.w), a0);
                a1 = FDOT2(u2h(wst[(size_t)(4 * bk + 3) * 1024]), u2h(hv.w), a1);
            }
        }
        float g0 = a0 + b0 + xg0;
        float g1 = a1 + b1 + xg1;
        float s0 = 1.f / (1.f + expf(-g0));                         // c0: gates i/f -> sigmoid
        float s1 = (tid < 256) ? tanhf(g1) : 1.f / (1.f + expf(-g1)); // c1: g -> tanh, o -> sigmoid
        gbuf[tid] = s0;
        gbuf[512 + tid] = s1;
        __syncthreads();

        if (tid < 256) {
            float iv = gbuf[tid], fv = gbuf[256 + tid];
            float gv = gbuf[512 + tid], ov = gbuf[768 + tid];
            creg = fv * creg + iv * gv;
            hreg = ov * tanhf(creg);
            const int sgl = chunk * TCH + sl;
            const int tg = d ? (FRAMES - 1 - sgl) : sgl;
            hout[((size_t)(d * BATCH + b) * FRAMES + tg) * HID + tid] = hreg;
            hh_u16[tid] = f16b(hreg);
        }
        __syncthreads();
        xg0 = xg0n; xg1 = xg1n;
    }
    if (tid < 256) {
        hstate[(size_t)g * 256 + tid] = hreg;
        cstate[(size_t)g * 256 + tid] = creg;
    }
}

// ---------- dropout(0.5) + ReLU + concat, JAX partitionable threefry ----------
__global__ __launch_bounds__(256) void k_dropout(const float* __restrict__ h,
                                                 unsigned short* __restrict__ xh,  // may be null
                                                 unsigned short* __restrict__ xl,  // may be null
                                                 float* __restrict__ xf,           // may be null
                                                 uint32_t fk0, uint32_t fk1) {
    uint32_t i = blockIdx.x * 256u + threadIdx.x;    // grid 65536 -> NMASK threads
    uint32_t o0, o1;
    tf2x32(fk0, fk1, 0u, i, o0, o1);
    uint32_t bits = o0 ^ o1;
    uint32_t f = i & 511u;
    uint32_t t = (i >> 9) & 1023u;
    uint32_t b = i >> 19;                            // 0..31
    uint32_t dv = f >> 8, n = f & 255u;
    float v = h[(((size_t)dv * BATCH + b) * FRAMES + t) * HID + n];
    float o = (((bits >> 31) == 0u) && v > 0.f) ? 2.f * v : 0.f;
    if (xh != nullptr) {
        unsigned short hb_ = f2bf(o);
        xh[i] = hb_;
        xl[i] = f2bf(o - b2f(hb_));
    }
    if (xf != nullptr) xf[i] = o;
}

// ---------- output projection: out[32768][29] = Xf[32768][512] @ Wout + bout ----------
__global__ __launch_bounds__(256) void k_out(const float* __restrict__ xf,
                                             const float* __restrict__ Wout,
                                             const float* __restrict__ bout,
                                             float* __restrict__ out) {
    __shared__ __align__(16) float Xs[64][68];
    const int tid = threadIdx.x;
    const int r = tid & 63, cg = tid >> 6;           // 4 col-groups of 8 (last has 5)
    const int row0 = blockIdx.x * 64;
    float acc[8] = {0.f, 0.f, 0.f, 0.f, 0.f, 0.f, 0.f, 0.f};
    for (int kc = 0; kc < 512; kc += 64) {
        int sr = tid >> 2, sc = (tid & 3) * 16;
        const float* src = xf + (size_t)(row0 + sr) * 512 + kc + sc;
        *reinterpret_cast<float4*>(&Xs[sr][sc])      = *reinterpret_cast<const float4*>(src);
        *reinterpret_cast<float4*>(&Xs[sr][sc + 4])  = *reinterpret_cast<const float4*>(src + 4);
        *reinterpret_cast<float4*>(&Xs[sr][sc + 8])  = *reinterpret_cast<const float4*>(src + 8);
        *reinterpret_cast<float4*>(&Xs[sr][sc + 12]) = *reinterpret_cast<const float4*>(src + 12);
        __syncthreads();
        for (int k = 0; k < 64; ++k) {
            float xv = Xs[r][k];
            const float* wr = Wout + (size_t)(kc + k) * NCLS + cg * 8;
            #pragma unroll
            for (int cc = 0; cc < 8; ++cc)
                if (cg * 8 + cc < NCLS) acc[cc] = fmaf(xv, wr[cc], acc[cc]);
        }
        __syncthreads();
    }
    for (int cc = 0; cc < 8; ++cc) {
        int col = cg * 8 + cc;
        if (col < NCLS) out[(size_t)(row0 + r) * NCLS + col] = acc[cc] + bout[col];
    }
}

// ---------- launch ----------
extern "C" void kernel_launch(void* const* d_in, const int* in_sizes, int n_in,
                              void* d_out, int out_size, void* d_ws, size_t ws_size,
                              hipStream_t stream) {
    const float* sig  = (const float*)d_in[0];
    const float* Wih  = (const float*)d_in[1];
    const float* Whh  = (const float*)d_in[2];
    const float* bias = (const float*)d_in[3];
    const float* Wout = (const float*)d_in[4];
    const float* bout = (const float*)d_in[5];
    float* out = (float*)d_out;

    char* ws = (char*)d_ws;
    size_t off = 0;
    auto alloc = [&](size_t bytes) -> void* {
        void* p = ws + off;
        off += (bytes + 255) & ~(size_t)255;
        return p;
    };
    float* psum           = (float*)alloc(1024 * 4);
    float* psq            = (float*)alloc(1024 * 4);
    float* mu             = (float*)alloc(32 * 4);
    float* rstd           = (float*)alloc(32 * 4);
    unsigned short* WThi  = (unsigned short*)alloc((size_t)6 * 1024 * 512 * 2);     // 6.3 MB
    unsigned short* WTlo  = (unsigned short*)alloc((size_t)6 * 1024 * 512 * 2);     // 6.3 MB
    uint32_t* Wkm         = (uint32_t*)alloc((size_t)6 * 128 * 1024 * 4);           // 3.1 MB
    unsigned short* xhi   = (unsigned short*)alloc((size_t)MROWS * 512 * 2);        // 33.5 MB
    unsigned short* xlo   = (unsigned short*)alloc((size_t)MROWS * 512 * 2);        // 33.5 MB
    float* xgA            = (float*)alloc((size_t)BATCH * TCH * 1024 * 4);          // 33.5 MB
    float* xgB            = (float*)alloc((size_t)BATCH * TCH * 1024 * 4);          // 33.5 MB
    float* hb             = (float*)alloc((size_t)2 * BATCH * FRAMES * HID * 4);    // 67 MB
    float* hstate         = (float*)alloc((size_t)64 * HID * 4);
    float* cstate         = (float*)alloc((size_t)64 * HID * 4);
    // Total ~218 MB (round-4 proven layout).
    float* xf32           = (float*)xhi;   // layer-2 fp32 activations overlay dead xhi/xlo

    k_stats1<<<1024, 256, 0, stream>>>(sig, psum, psq);
    k_stats2<<<1, 1024, 0, stream>>>(psum, psq, mu, rstd);
    k_norm<<<16384, 256, 0, stream>>>(sig, mu, rstd, xhi, xlo);
    k_wih_t<<<12288, 256, 0, stream>>>(Wih, WThi, WTlo);
    k_wkm<<<3072, 256, 0, stream>>>(Whh, Wkm);

    for (int l = 0; l < 3; ++l) {
        const unsigned short* Bh0 = WThi + (size_t)(l * 2 + 0) * 1024 * 512;
        const unsigned short* Bl0 = WTlo + (size_t)(l * 2 + 0) * 1024 * 512;
        const unsigned short* Bh1 = WThi + (size_t)(l * 2 + 1) * 1024 * 512;
        const unsigned short* Bl1 = WTlo + (size_t)(l * 2 + 1) * 1024 * 512;
        for (int c = 0; c < NCHUNK; ++c) {
            dim3 gg(8, 64);
            int t0f = c * TCH;
            int t0b = (NCHUNK - 1 - c) * TCH;
            k_gemm_chunk<<<gg, 256, 0, stream>>>(xhi, xlo, Bh0, Bl0, xgA, t0f);
            k_gemm_chunk<<<gg, 256, 0, stream>>>(xhi, xlo, Bh1, Bl1, xgB, t0b);
            k_scan3<<<64, 512, 0, stream>>>(Wkm, bias, xgA, xgB, hb, hstate, cstate, l, c);
        }
        uint32_t fk0, fk1;
        tf2x32(0u, 42u, 0u, (uint32_t)l, fk0, fk1);
        if (l < 2)
            k_dropout<<<65536, 256, 0, stream>>>(hb, xhi, xlo, nullptr, fk0, fk1);
        else
            k_dropout<<<65536, 256, 0, stream>>>(hb, nullptr, nullptr, xf32, fk0, fk1);
    }
    k_out<<<512, 256, 0, stream>>>(xf32, Wout, bout, out);
}

// Round 7
// 58472.626 us; speedup vs baseline: 1.6127x; 1.0779x over previous
//
#include <hip/hip_runtime.h>
#include <cstdint>
#include <cstddef>

// ---------- small helpers ----------
typedef __bf16 bf16x8 __attribute__((ext_vector_type(8)));
typedef float  f32x4  __attribute__((ext_vector_type(4)));
typedef _Float16 h2 __attribute__((ext_vector_type(2)));

__device__ __forceinline__ float b2f(unsigned short u) {
    union { uint32_t i; float f; } x; x.i = ((uint32_t)u) << 16; return x.f;
}
__device__ __forceinline__ unsigned short f2bf(float f) {
    uint32_t u = __float_as_uint(f);
    uint32_t r = (u + 0x7FFFu + ((u >> 16) & 1u)) >> 16;   // RNE, no NaN in data
    return (unsigned short)r;
}
__device__ __forceinline__ uint32_t packf16(float a, float b) {
    union { _Float16 h[2]; uint32_t u; } x;
    x.h[0] = (_Float16)a; x.h[1] = (_Float16)b; return x.u;
}
__device__ __forceinline__ h2 u2h(uint32_t u) {
    union { uint32_t u; h2 v; } x; x.u = u; return x.v;
}
__device__ __forceinline__ unsigned short f16b(float f) {
    union { _Float16 h; unsigned short u; } x; x.h = (_Float16)f; return x.u;
}

#if __has_builtin(__builtin_amdgcn_fdot2)
#define FDOT2(w, hh, acc) __builtin_amdgcn_fdot2((w), (hh), (acc), false)
#else
__device__ __forceinline__ float fdot2_sw(h2 a, h2 b, float c) {
    return c + (float)a[0] * (float)b[0] + (float)a[1] * (float)b[1];
}
#define FDOT2(w, hh, acc) fdot2_sw((w), (hh), (acc))
#endif

// JAX threefry2x32 (20 rounds), usable host+device
__host__ __device__ inline void tf2x32(uint32_t k0, uint32_t k1,
                                       uint32_t x0, uint32_t x1,
                                       uint32_t& o0, uint32_t& o1) {
    uint32_t ks2 = k0 ^ k1 ^ 0x1BD11BDAu;
#define TF_ROT(x,n) (((x) << (n)) | ((x) >> (32 - (n))))
#define TF_RND(r) { x0 += x1; x1 = TF_ROT(x1, r); x1 ^= x0; }
    x0 += k0; x1 += k1;
    TF_RND(13) TF_RND(15) TF_RND(26) TF_RND(6)
    x0 += k1; x1 += ks2 + 1u;
    TF_RND(17) TF_RND(29) TF_RND(16) TF_RND(24)
    x0 += ks2; x1 += k0 + 2u;
    TF_RND(13) TF_RND(15) TF_RND(26) TF_RND(6)
    x0 += k0; x1 += k1 + 3u;
    TF_RND(17) TF_RND(29) TF_RND(16) TF_RND(24)
    x0 += k1; x1 += ks2 + 4u;
    TF_RND(13) TF_RND(15) TF_RND(26) TF_RND(6)
    x0 += ks2; x1 += k0 + 5u;
    o0 = x0; o1 = x1;
#undef TF_RND
#undef TF_ROT
}

// ---------- constants ----------
#define BATCH 32
#define TSAMP 524288
#define FRAMES 1024
#define HID 256
#define GATES 1024            // 4*HID
#define MROWS 32768           // BATCH*FRAMES
#define NCLS 29
#define NMASK 16777216u       // 32*1024*512
#define TCH 256               // time chunk
#define NCHUNK 4

// ---------- stats: per-batch mean / 1/(std+eps) ----------
__global__ __launch_bounds__(256) void k_stats1(const float* __restrict__ sig,
                                                float* __restrict__ psum,
                                                float* __restrict__ psq) {
    int blk = blockIdx.x;               // 1024 blocks, 32 per batch
    int tid = threadIdx.x;
    size_t base = (size_t)blk * 16384;
    float s = 0.f, q = 0.f;
    for (int i = 0; i < 16; ++i) {
        float4 v = *reinterpret_cast<const float4*>(sig + base + ((size_t)i * 256 + tid) * 4);
        s += v.x + v.y + v.z + v.w;
        q += v.x * v.x + v.y * v.y + v.z * v.z + v.w * v.w;
    }
    __shared__ float ls[4], lq[4];
    int w = tid >> 6, lane = tid & 63;
    for (int m = 32; m; m >>= 1) { s += __shfl_down(s, m); q += __shfl_down(q, m); }
    if (lane == 0) { ls[w] = s; lq[w] = q; }
    __syncthreads();
    if (tid == 0) {
        psum[blk] = ls[0] + ls[1] + ls[2] + ls[3];
        psq[blk]  = lq[0] + lq[1] + lq[2] + lq[3];
    }
}

__global__ __launch_bounds__(1024) void k_stats2(const float* __restrict__ psum,
                                                 const float* __restrict__ psq,
                                                 float* __restrict__ mu,
                                                 float* __restrict__ rstd) {
    int tid = threadIdx.x;              // 1024 = 32 batches * 32 chunks
    float s = psum[tid], q = psq[tid];
    for (int m = 16; m; m >>= 1) { s += __shfl_down(s, m); q += __shfl_down(q, m); }
    if ((tid & 31) == 0) {
        int b = tid >> 5;
        float m_ = s * (1.f / (float)TSAMP);
        float v  = q * (1.f / (float)TSAMP) - m_ * m_;
        float sd = sqrtf(fmaxf(v, 0.f));
        mu[b] = m_;
        rstd[b] = 1.f / (sd + 1e-8f);
    }
}

// ---------- normalize + frame -> bf16 hi/lo pair [32768][512] ----------
__global__ __launch_bounds__(256) void k_norm(const float* __restrict__ sig,
                                              const float* __restrict__ mu,
                                              const float* __restrict__ rstd,
                                              unsigned short* __restrict__ xh,
                                              unsigned short* __restrict__ xl) {
    size_t gid = (size_t)blockIdx.x * 256 + threadIdx.x;   // 4194304 threads, 4 elems each
    int b = (int)(gid >> 17);
    float m = mu[b], r = rstd[b];
    float4 v = *reinterpret_cast<const float4*>(sig + gid * 4);
    float f0 = (v.x - m) * r, f1 = (v.y - m) * r, f2 = (v.z - m) * r, f3 = (v.w - m) * r;
    ushort4 oh, ol;
    oh.x = f2bf(f0); ol.x = f2bf(f0 - b2f(oh.x));
    oh.y = f2bf(f1); ol.y = f2bf(f1 - b2f(oh.y));
    oh.z = f2bf(f2); ol.z = f2bf(f2 - b2f(oh.z));
    oh.w = f2bf(f3); ol.w = f2bf(f3 - b2f(oh.w));
    *reinterpret_cast<ushort4*>(xh + gid * 4) = oh;
    *reinterpret_cast<ushort4*>(xl + gid * 4) = ol;
}

// ---------- weight prep: Wih transpose + hi/lo split ----------
__global__ __launch_bounds__(256) void k_wih_t(const float* __restrict__ Wih,
                                               unsigned short* __restrict__ WTh,
                                               unsigned short* __restrict__ WTl) {
    size_t gid = (size_t)blockIdx.x * 256 + threadIdx.x;   // 3145728
    int k = (int)(gid & 511);
    int n = (int)((gid >> 9) & 1023);
    int ld = (int)(gid >> 19);
    float w = Wih[((size_t)ld * 512 + k) * 1024 + n];
    unsigned short h = f2bf(w);
    WTh[gid] = h;
    WTl[gid] = f2bf(w - b2f(h));
}

// ---------- weight prep: Whh -> packed fp16 pairs, layout [ld][kpair=128][col=1024] ----------
__global__ __launch_bounds__(256) void k_wkm(const float* __restrict__ W,
                                             uint32_t* __restrict__ Wkm) {
    size_t gid = (size_t)blockIdx.x * 256 + threadIdx.x;   // 786432
    int col = (int)(gid & 1023);
    int kk  = (int)((gid >> 10) & 127);
    int ld  = (int)(gid >> 17);
    float w0 = W[((size_t)ld * 256 + 2 * kk) * 1024 + col];
    float w1 = W[((size_t)ld * 256 + 2 * kk + 1) * 1024 + col];
    Wkm[gid] = packf16(w0, w1);
}

// ---------- chunked input GEMM (split-bf16 MFMA, fp32 out) ----------
__global__ __launch_bounds__(256) void k_gemm_chunk(const unsigned short* __restrict__ Ah,
                                                    const unsigned short* __restrict__ Al,
                                                    const unsigned short* __restrict__ BTh,
                                                    const unsigned short* __restrict__ BTl,
                                                    float* __restrict__ C,
                                                    int t0) {
    __shared__ __align__(16) unsigned short Ahs[128][40];
    __shared__ __align__(16) unsigned short Als[128][40];
    __shared__ __align__(16) unsigned short Bhs[128][40];
    __shared__ __align__(16) unsigned short Bls[128][40];
    const int tid = threadIdx.x;
    const int tm = blockIdx.y * 128;     // gridDim.y = 64  (8192 chunk rows)
    const int tn = blockIdx.x * 128;     // gridDim.x = 8   (1024 gate cols)
    const int lane = tid & 63, w = tid >> 6;
    const int wr = w >> 1, wc = w & 1;
    const int l15 = lane & 15, lk = (lane >> 4) * 8;
    f32x4 acc[4][4];
    for (int i = 0; i < 4; ++i)
        for (int j = 0; j < 4; ++j)
            acc[i][j] = (f32x4){0.f, 0.f, 0.f, 0.f};
    const int srow = tid >> 1, scol = (tid & 1) * 16;
    const int rg = tm + srow;
    const size_t am = (size_t)((rg >> 8) * 1024 + t0 + (rg & 255)) * 512;
    const size_t bm = (size_t)(tn + srow) * 512;
    for (int kt = 0; kt < 512; kt += 32) {
        *reinterpret_cast<uint4*>(&Ahs[srow][scol])     = *reinterpret_cast<const uint4*>(&Ah[am + kt + scol]);
        *reinterpret_cast<uint4*>(&Ahs[srow][scol + 8]) = *reinterpret_cast<const uint4*>(&Ah[am + kt + scol + 8]);
        *reinterpret_cast<uint4*>(&Als[srow][scol])     = *reinterpret_cast<const uint4*>(&Al[am + kt + scol]);
        *reinterpret_cast<uint4*>(&Als[srow][scol + 8]) = *reinterpret_cast<const uint4*>(&Al[am + kt + scol + 8]);
        *reinterpret_cast<uint4*>(&Bhs[srow][scol])     = *reinterpret_cast<const uint4*>(&BTh[bm + kt + scol]);
        *reinterpret_cast<uint4*>(&Bhs[srow][scol + 8]) = *reinterpret_cast<const uint4*>(&BTh[bm + kt + scol + 8]);
        *reinterpret_cast<uint4*>(&Bls[srow][scol])     = *reinterpret_cast<const uint4*>(&BTl[bm + kt + scol]);
        *reinterpret_cast<uint4*>(&Bls[srow][scol + 8]) = *reinterpret_cast<const uint4*>(&BTl[bm + kt + scol + 8]);
        __syncthreads();
        bf16x8 afh[4], afl[4], bfh[4], bfl[4];
        for (int m = 0; m < 4; ++m) {
            afh[m] = *reinterpret_cast<const bf16x8*>(&Ahs[wr * 64 + m * 16 + l15][lk]);
            afl[m] = *reinterpret_cast<const bf16x8*>(&Als[wr * 64 + m * 16 + l15][lk]);
        }
        for (int n = 0; n < 4; ++n) {
            bfh[n] = *reinterpret_cast<const bf16x8*>(&Bhs[wc * 64 + n * 16 + l15][lk]);
            bfl[n] = *reinterpret_cast<const bf16x8*>(&Bls[wc * 64 + n * 16 + l15][lk]);
        }
        for (int m = 0; m < 4; ++m)
            for (int n = 0; n < 4; ++n) {
                acc[m][n] = __builtin_amdgcn_mfma_f32_16x16x32_bf16(afh[m], bfh[n], acc[m][n], 0, 0, 0);
                acc[m][n] = __builtin_amdgcn_mfma_f32_16x16x32_bf16(afl[m], bfh[n], acc[m][n], 0, 0, 0);
                acc[m][n] = __builtin_amdgcn_mfma_f32_16x16x32_bf16(afh[m], bfl[n], acc[m][n], 0, 0, 0);
            }
        __syncthreads();
    }
    const int rbase = tm + wr * 64 + (lane >> 4) * 4;
    const int cbase = tn + wc * 64 + l15;
    for (int m = 0; m < 4; ++m)
        for (int n = 0; n < 4; ++n)
            for (int r = 0; r < 4; ++r) {
                int row = rbase + m * 16 + r;
                int col = cbase + n * 16;
                C[(size_t)row * 1024 + col] = acc[m][n][r];
            }
}

// ---------- LSTM scan: one block per (dir,batch); W on-chip ----------
// 64 blocks x 512 threads, __launch_bounds__(512,1): 1 block/CU (LDS-forced),
// VGPR cap 256 -> wr[128] stays in registers (round-6 spill fix: VGPR_Count was 128).
// Thread t owns gate columns c0 = t (REGISTERS, 128 packed fp16 pairs) and
// c1 = 512+t (t<256: LDS-resident, b128 reads w/ G4 XOR swizzle; t>=256: L2-streamed).
// h carried as fp16 pairs in LDS; dot via v_dot2_f32_f16 (exact fp32 accum).
// No cross-block communication (round-5 lesson).
__global__ __launch_bounds__(512, 1) void k_scan3(const uint32_t* __restrict__ Wkm,  // [ld][128][1024]
                                                  const float* __restrict__ bias,
                                                  const float* __restrict__ xgA,    // fwd [32][256][1024]
                                                  const float* __restrict__ xgB,    // bwd [32][256][1024]
                                                  float* __restrict__ hout,
                                                  float* __restrict__ hstate,       // [64][256]
                                                  float* __restrict__ cstate,       // [64][256]
                                                  int layer, int chunk) {
    const int g = blockIdx.x;                   // 0..63
    const int d = g >> 5, b = g & 31;
    const int tid = threadIdx.x;                // 0..511
    const int ld = layer * 2 + d;

    // Wlds: cols 512..767 (local c = 0..255), per-col contiguous 512B,
    // 16B slot s (4 kpairs) stored at slot index s ^ (c & 7)  [G4 swizzle].
    __shared__ __align__(16) uint32_t Wlds[128 * 256];   // 128 KB
    __shared__ __align__(16) float gbuf[GATES];          // 4 KB
    __shared__ __align__(16) unsigned short hh_u16[HID]; // h as fp16, 512 B

    const uint32_t* Wld = Wkm + (size_t)ld * 131072;

    // ---- stage LDS cols (global coalesced reads; swizzled writes, one-time) ----
    for (int idx = tid; idx < 128 * 256; idx += 512) {
        int kk = idx >> 8, c = idx & 255;
        int s = kk >> 2, j = kk & 3;
        Wlds[(c << 7) + ((s ^ (c & 7)) << 2) + j] = Wld[(size_t)kk * 1024 + 512 + c];
    }
    // ---- stage register cols (col = tid): 128 coalesced b32 loads ----
    uint32_t wr[128];
    {
        const uint32_t* gc = Wld + tid;
        #pragma unroll
        for (int kk = 0; kk < 128; ++kk)
            wr[kk] = gc[(size_t)kk * 1024];
    }
    const float b0 = bias[(size_t)ld * 1024 + tid];
    const float b1 = bias[(size_t)ld * 1024 + 512 + tid];

    float creg = 0.f, hreg = 0.f;
    if (tid < HID) {
        if (chunk != 0) {
            hreg = hstate[(size_t)g * 256 + tid];
            creg = cstate[(size_t)g * 256 + tid];
        }
        hh_u16[tid] = f16b(hreg);
    }
    __syncthreads();

    const float* xbase = (d ? xgB : xgA) + (size_t)b * TCH * 1024;
    const uint32_t* wst = Wld + 512 + tid;      // streamed col (only used by tid>=256)
    const uint4* hh4 = reinterpret_cast<const uint4*>(hh_u16);
    const int swz = (tid & 7);                  // swizzle key for LDS path (c = tid)

    const int tl0 = d ? (TCH - 1) : 0, tstep = d ? -1 : 1;
    float xg0 = xbase[(size_t)tl0 * 1024 + tid];
    float xg1 = xbase[(size_t)tl0 * 1024 + 512 + tid];

    for (int sl = 0; sl < TCH; ++sl) {
        // prefetch next step's xg (independent of h)
        float xg0n = xg0, xg1n = xg1;
        if (sl + 1 < TCH) {
            size_t r = (size_t)(tl0 + tstep * (sl + 1)) * 1024;
            xg0n = xbase[r + tid];
            xg1n = xbase[r + 512 + tid];
        }

        float a0 = 0.f, a1 = 0.f;
        if (tid < 256) {
            const uint32_t* wcol = &Wlds[tid << 7];
            #pragma unroll
            for (int s = 0; s < 32; ++s) {
                uint4 hv = hh4[s];
                uint4 wv = *reinterpret_cast<const uint4*>(wcol + ((s ^ swz) << 2));
                a0 = FDOT2(u2h(wr[4 * s + 0]), u2h(hv.x), a0);
                a1 = FDOT2(u2h(wv.x), u2h(hv.x), a1);
                a0 = FDOT2(u2h(wr[4 * s + 1]), u2h(hv.y), a0);
                a1 = FDOT2(u2h(wv.y), u2h(hv.y), a1);
                a0 = FDOT2(u2h(wr[4 * s + 2]), u2h(hv.z), a0);
                a1 = FDOT2(u2h(wv.z), u2h(hv.z), a1);
                a0 = FDOT2(u2h(wr[4 * s + 3]), u2h(hv.w), a0);
                a1 = FDOT2(u2h(wv.w), u2h(hv.w), a1);
            }
        } else {
            #pragma unroll
            for (int bk = 0; bk < 32; ++bk) {
                uint4 hv = hh4[bk];
                a0 = FDOT2(u2h(wr[4 * bk + 0]), u2h(hv.x), a0);
                a1 = FDOT2(u2h(wst[(size_t)(4 * bk + 0) * 1024]), u2h(hv.x), a1);
                a0 = FDOT2(u2h(wr[4 * bk + 1]), u2h(hv.y), a0);
                a1 = FDOT2(u2h(wst[(size_t)(4 * bk + 1) * 1024]), u2h(hv.y), a1);
                a0 = FDOT2(u2h(wr[4 * bk + 2]), u2h(hv.z), a0);
                a1 = FDOT2(u2h(wst[(size_t)(4 * bk + 2) * 1024]), u2h(hv.z), a1);
                a0 = FDOT2(u2h(wr[4 * bk + 3]), u2h(hv.w), a0);
                a1 = FDOT2(u2h(wst[(size_t)(4 * bk + 3) * 1024]), u2h(hv.w), a1);
            }
        }
        float g0 = a0 + b0 + xg0;
        float g1 = a1 + b1 + xg1;
        float s0 = 1.f / (1.f + expf(-g0));                           // c0: i (t<256) / f (t>=256)
        float s1 = (tid < 256) ? tanhf(g1) : 1.f / (1.f + expf(-g1)); // c1: g -> tanh, o -> sigmoid
        gbuf[tid] = s0;
        gbuf[512 + tid] = s1;
        __syncthreads();

        if (tid < 256) {
            float iv = gbuf[tid], fv = gbuf[256 + tid];
            float gv = gbuf[512 + tid], ov = gbuf[768 + tid];
            creg = fv * creg + iv * gv;
            hreg = ov * tanhf(creg);
            const int sgl = chunk * TCH + sl;
            const int tg = d ? (FRAMES - 1 - sgl) : sgl;
            hout[((size_t)(d * BATCH + b) * FRAMES + tg) * HID + tid] = hreg;
            hh_u16[tid] = f16b(hreg);
        }
        __syncthreads();
        xg0 = xg0n; xg1 = xg1n;
    }
    if (tid < 256) {
        hstate[(size_t)g * 256 + tid] = hreg;
        cstate[(size_t)g * 256 + tid] = creg;
    }
}

// ---------- dropout(0.5) + ReLU + concat, JAX partitionable threefry ----------
__global__ __launch_bounds__(256) void k_dropout(const float* __restrict__ h,
                                                 unsigned short* __restrict__ xh,  // may be null
                                                 unsigned short* __restrict__ xl,  // may be null
                                                 float* __restrict__ xf,           // may be null
                                                 uint32_t fk0, uint32_t fk1) {
    uint32_t i = blockIdx.x * 256u + threadIdx.x;    // grid 65536 -> NMASK threads
    uint32_t o0, o1;
    tf2x32(fk0, fk1, 0u, i, o0, o1);
    uint32_t bits = o0 ^ o1;
    uint32_t f = i & 511u;
    uint32_t t = (i >> 9) & 1023u;
    uint32_t b = i >> 19;                            // 0..31
    uint32_t dv = f >> 8, n = f & 255u;
    float v = h[(((size_t)dv * BATCH + b) * FRAMES + t) * HID + n];
    float o = (((bits >> 31) == 0u) && v > 0.f) ? 2.f * v : 0.f;
    if (xh != nullptr) {
        unsigned short hb_ = f2bf(o);
        xh[i] = hb_;
        xl[i] = f2bf(o - b2f(hb_));
    }
    if (xf != nullptr) xf[i] = o;
}

// ---------- output projection: out[32768][29] = Xf[32768][512] @ Wout + bout ----------
__global__ __launch_bounds__(256) void k_out(const float* __restrict__ xf,
                                             const float* __restrict__ Wout,
                                             const float* __restrict__ bout,
                                             float* __restrict__ out) {
    __shared__ __align__(16) float Xs[64][68];
    const int tid = threadIdx.x;
    const int r = tid & 63, cg = tid >> 6;           // 4 col-groups of 8 (last has 5)
    const int row0 = blockIdx.x * 64;
    float acc[8] = {0.f, 0.f, 0.f, 0.f, 0.f, 0.f, 0.f, 0.f};
    for (int kc = 0; kc < 512; kc += 64) {
        int sr = tid >> 2, sc = (tid & 3) * 16;
        const float* src = xf + (size_t)(row0 + sr) * 512 + kc + sc;
        *reinterpret_cast<float4*>(&Xs[sr][sc])      = *reinterpret_cast<const float4*>(src);
        *reinterpret_cast<float4*>(&Xs[sr][sc + 4])  = *reinterpret_cast<const float4*>(src + 4);
        *reinterpret_cast<float4*>(&Xs[sr][sc + 8])  = *reinterpret_cast<const float4*>(src + 8);
        *reinterpret_cast<float4*>(&Xs[sr][sc + 12]) = *reinterpret_cast<const float4*>(src + 12);
        __syncthreads();
        for (int k = 0; k < 64; ++k) {
            float xv = Xs[r][k];
            const float* wr = Wout + (size_t)(kc + k) * NCLS + cg * 8;
            #pragma unroll
            for (int cc = 0; cc < 8; ++cc)
                if (cg * 8 + cc < NCLS) acc[cc] = fmaf(xv, wr[cc], acc[cc]);
        }
        __syncthreads();
    }
    for (int cc = 0; cc < 8; ++cc) {
        int col = cg * 8 + cc;
        if (col < NCLS) out[(size_t)(row0 + r) * NCLS + col] = acc[cc] + bout[col];
    }
}

// ---------- launch ----------
extern "C" void kernel_launch(void* const* d_in, const int* in_sizes, int n_in,
                              void* d_out, int out_size, void* d_ws, size_t ws_size,
                              hipStream_t stream) {
    const float* sig  = (const float*)d_in[0];
    const float* Wih  = (const float*)d_in[1];
    const float* Whh  = (const float*)d_in[2];
    const float* bias = (const float*)d_in[3];
    const float* Wout = (const float*)d_in[4];
    const float* bout = (const float*)d_in[5];
    float* out = (float*)d_out;

    char* ws = (char*)d_ws;
    size_t off = 0;
    auto alloc = [&](size_t bytes) -> void* {
        void* p = ws + off;
        off += (bytes + 255) & ~(size_t)255;
        return p;
    };
    float* psum           = (float*)alloc(1024 * 4);
    float* psq            = (float*)alloc(1024 * 4);
    float* mu             = (float*)alloc(32 * 4);
    float* rstd           = (float*)alloc(32 * 4);
    unsigned short* WThi  = (unsigned short*)alloc((size_t)6 * 1024 * 512 * 2);     // 6.3 MB
    unsigned short* WTlo  = (unsigned short*)alloc((size_t)6 * 1024 * 512 * 2);     // 6.3 MB
    uint32_t* Wkm         = (uint32_t*)alloc((size_t)6 * 128 * 1024 * 4);           // 3.1 MB
    unsigned short* xhi   = (unsigned short*)alloc((size_t)MROWS * 512 * 2);        // 33.5 MB
    unsigned short* xlo   = (unsigned short*)alloc((size_t)MROWS * 512 * 2);        // 33.5 MB
    float* xgA            = (float*)alloc((size_t)BATCH * TCH * 1024 * 4);          // 33.5 MB
    float* xgB            = (float*)alloc((size_t)BATCH * TCH * 1024 * 4);          // 33.5 MB
    float* hb             = (float*)alloc((size_t)2 * BATCH * FRAMES * HID * 4);    // 67 MB
    float* hstate         = (float*)alloc((size_t)64 * HID * 4);
    float* cstate         = (float*)alloc((size_t)64 * HID * 4);
    // Total ~218 MB (round-4/6 proven layout).
    float* xf32           = (float*)xhi;   // layer-2 fp32 activations overlay dead xhi/xlo

    k_stats1<<<1024, 256, 0, stream>>>(sig, psum, psq);
    k_stats2<<<1, 1024, 0, stream>>>(psum, psq, mu, rstd);
    k_norm<<<16384, 256, 0, stream>>>(sig, mu, rstd, xhi, xlo);
    k_wih_t<<<12288, 256, 0, stream>>>(Wih, WThi, WTlo);
    k_wkm<<<3072, 256, 0, stream>>>(Whh, Wkm);

    for (int l = 0; l < 3; ++l) {
        const unsigned short* Bh0 = WThi + (size_t)(l * 2 + 0) * 1024 * 512;
        const unsigned short* Bl0 = WTlo + (size_t)(l * 2 + 0) * 1024 * 512;
        const unsigned short* Bh1 = WThi + (size_t)(l * 2 + 1) * 1024 * 512;
        const unsigned short* Bl1 = WTlo + (size_t)(l * 2 + 1) * 1024 * 512;
        for (int c = 0; c < NCHUNK; ++c) {
            dim3 gg(8, 64);
            int t0f = c * TCH;
            int t0b = (NCHUNK - 1 - c) * TCH;
            k_gemm_chunk<<<gg, 256, 0, stream>>>(xhi, xlo, Bh0, Bl0, xgA, t0f);
            k_gemm_chunk<<<gg, 256, 0, stream>>>(xhi, xlo, Bh1, Bl1, xgB, t0b);
            k_scan3<<<64, 512, 0, stream>>>(Wkm, bias, xgA, xgB, hb, hstate, cstate, l, c);
        }
        uint32_t fk0, fk1;
        tf2x32(0u, 42u, 0u, (uint32_t)l, fk0, fk1);
        if (l < 2)
            k_dropout<<<65536, 256, 0, stream>>>(hb, xhi, xlo, nullptr, fk0, fk1);
        else
            k_dropout<<<65536, 256, 0, stream>>>(hb, nullptr, nullptr, xf32, fk0, fk1);
    }
    k_out<<<512, 256, 0, stream>>>(xf32, Wout, bout, out);
}

// Round 8
// 24856.601 us; speedup vs baseline: 3.7936x; 2.3524x over previous
//
#include <hip/hip_runtime.h>
#include <cstdint>
#include <cstddef>

// ---------- small helpers ----------
typedef __bf16 bf16x8 __attribute__((ext_vector_type(8)));
typedef float  f32x4  __attribute__((ext_vector_type(4)));
typedef _Float16 h2 __attribute__((ext_vector_type(2)));

__device__ __forceinline__ float b2f(unsigned short u) {
    union { uint32_t i; float f; } x; x.i = ((uint32_t)u) << 16; return x.f;
}
__device__ __forceinline__ unsigned short f2bf(float f) {
    uint32_t u = __float_as_uint(f);
    uint32_t r = (u + 0x7FFFu + ((u >> 16) & 1u)) >> 16;   // RNE, no NaN in data
    return (unsigned short)r;
}
__device__ __forceinline__ uint32_t packf16(float a, float b) {
    union { _Float16 h[2]; uint32_t u; } x;
    x.h[0] = (_Float16)a; x.h[1] = (_Float16)b; return x.u;
}
__device__ __forceinline__ h2 u2h(uint32_t u) {
    union { uint32_t u; h2 v; } x; x.u = u; return x.v;
}
__device__ __forceinline__ unsigned short f16b(float f) {
    union { _Float16 h; unsigned short u; } x; x.h = (_Float16)f; return x.u;
}

#if __has_builtin(__builtin_amdgcn_fdot2)
#define FDOT2(w, hh, acc) __builtin_amdgcn_fdot2((w), (hh), (acc), false)
#else
__device__ __forceinline__ float fdot2_sw(h2 a, h2 b, float c) {
    return c + (float)a[0] * (float)b[0] + (float)a[1] * (float)b[1];
}
#define FDOT2(w, hh, acc) fdot2_sw((w), (hh), (acc))
#endif

// JAX threefry2x32 (20 rounds), usable host+device
__host__ __device__ inline void tf2x32(uint32_t k0, uint32_t k1,
                                       uint32_t x0, uint32_t x1,
                                       uint32_t& o0, uint32_t& o1) {
    uint32_t ks2 = k0 ^ k1 ^ 0x1BD11BDAu;
#define TF_ROT(x,n) (((x) << (n)) | ((x) >> (32 - (n))))
#define TF_RND(r) { x0 += x1; x1 = TF_ROT(x1, r); x1 ^= x0; }
    x0 += k0; x1 += k1;
    TF_RND(13) TF_RND(15) TF_RND(26) TF_RND(6)
    x0 += k1; x1 += ks2 + 1u;
    TF_RND(17) TF_RND(29) TF_RND(16) TF_RND(24)
    x0 += ks2; x1 += k0 + 2u;
    TF_RND(13) TF_RND(15) TF_RND(26) TF_RND(6)
    x0 += k0; x1 += k1 + 3u;
    TF_RND(17) TF_RND(29) TF_RND(16) TF_RND(24)
    x0 += k1; x1 += ks2 + 4u;
    TF_RND(13) TF_RND(15) TF_RND(26) TF_RND(6)
    x0 += ks2; x1 += k0 + 5u;
    o0 = x0; o1 = x1;
#undef TF_RND
#undef TF_ROT
}

// ---------- constants ----------
#define BATCH 32
#define TSAMP 524288
#define FRAMES 1024
#define HID 256
#define GATES 1024            // 4*HID
#define MROWS 32768           // BATCH*FRAMES
#define NCLS 29
#define NMASK 16777216u       // 32*1024*512
#define TCH 256               // time chunk
#define NCHUNK 4

// ---------- stats: per-batch mean / 1/(std+eps) ----------
__global__ __launch_bounds__(256) void k_stats1(const float* __restrict__ sig,
                                                float* __restrict__ psum,
                                                float* __restrict__ psq) {
    int blk = blockIdx.x;               // 1024 blocks, 32 per batch
    int tid = threadIdx.x;
    size_t base = (size_t)blk * 16384;
    float s = 0.f, q = 0.f;
    for (int i = 0; i < 16; ++i) {
        float4 v = *reinterpret_cast<const float4*>(sig + base + ((size_t)i * 256 + tid) * 4);
        s += v.x + v.y + v.z + v.w;
        q += v.x * v.x + v.y * v.y + v.z * v.z + v.w * v.w;
    }
    __shared__ float ls[4], lq[4];
    int w = tid >> 6, lane = tid & 63;
    for (int m = 32; m; m >>= 1) { s += __shfl_down(s, m); q += __shfl_down(q, m); }
    if (lane == 0) { ls[w] = s; lq[w] = q; }
    __syncthreads();
    if (tid == 0) {
        psum[blk] = ls[0] + ls[1] + ls[2] + ls[3];
        psq[blk]  = lq[0] + lq[1] + lq[2] + lq[3];
    }
}

__global__ __launch_bounds__(1024) void k_stats2(const float* __restrict__ psum,
                                                 const float* __restrict__ psq,
                                                 float* __restrict__ mu,
                                                 float* __restrict__ rstd) {
    int tid = threadIdx.x;              // 1024 = 32 batches * 32 chunks
    float s = psum[tid], q = psq[tid];
    for (int m = 16; m; m >>= 1) { s += __shfl_down(s, m); q += __shfl_down(q, m); }
    if ((tid & 31) == 0) {
        int b = tid >> 5;
        float m_ = s * (1.f / (float)TSAMP);
        float v  = q * (1.f / (float)TSAMP) - m_ * m_;
        float sd = sqrtf(fmaxf(v, 0.f));
        mu[b] = m_;
        rstd[b] = 1.f / (sd + 1e-8f);
    }
}

// ---------- normalize + frame -> bf16 hi/lo pair [32768][512] ----------
__global__ __launch_bounds__(256) void k_norm(const float* __restrict__ sig,
                                              const float* __restrict__ mu,
                                              const float* __restrict__ rstd,
                                              unsigned short* __restrict__ xh,
                                              unsigned short* __restrict__ xl) {
    size_t gid = (size_t)blockIdx.x * 256 + threadIdx.x;   // 4194304 threads, 4 elems each
    int b = (int)(gid >> 17);
    float m = mu[b], r = rstd[b];
    float4 v = *reinterpret_cast<const float4*>(sig + gid * 4);
    float f0 = (v.x - m) * r, f1 = (v.y - m) * r, f2 = (v.z - m) * r, f3 = (v.w - m) * r;
    ushort4 oh, ol;
    oh.x = f2bf(f0); ol.x = f2bf(f0 - b2f(oh.x));
    oh.y = f2bf(f1); ol.y = f2bf(f1 - b2f(oh.y));
    oh.z = f2bf(f2); ol.z = f2bf(f2 - b2f(oh.z));
    oh.w = f2bf(f3); ol.w = f2bf(f3 - b2f(oh.w));
    *reinterpret_cast<ushort4*>(xh + gid * 4) = oh;
    *reinterpret_cast<ushort4*>(xl + gid * 4) = ol;
}

// ---------- weight prep: Wih transpose + hi/lo split ----------
__global__ __launch_bounds__(256) void k_wih_t(const float* __restrict__ Wih,
                                               unsigned short* __restrict__ WTh,
                                               unsigned short* __restrict__ WTl) {
    size_t gid = (size_t)blockIdx.x * 256 + threadIdx.x;   // 3145728
    int k = (int)(gid & 511);
    int n = (int)((gid >> 9) & 1023);
    int ld = (int)(gid >> 19);
    float w = Wih[((size_t)ld * 512 + k) * 1024 + n];
    unsigned short h = f2bf(w);
    WTh[gid] = h;
    WTl[gid] = f2bf(w - b2f(h));
}

// ---------- weight prep: Whh -> packed fp16 pairs, uint2 layout [ld][kq=64][col=1024] ----------
// uint2 element (ld,kq,col) = { pack(k=4kq,4kq+1), pack(k=4kq+2,4kq+3) } of column col.
__global__ __launch_bounds__(256) void k_wkm(const float* __restrict__ W,
                                             uint32_t* __restrict__ Wkm) {
    uint32_t gid = blockIdx.x * 256u + threadIdx.x;        // 786432
    int j   = (int)(gid & 1);
    int col = (int)((gid >> 1) & 1023);
    int kq  = (int)((gid >> 11) & 63);
    int ld  = (int)(gid >> 17);
    int kp  = 2 * kq + j;                                  // kpair index
    float w0 = W[((size_t)ld * 256 + 2 * kp) * 1024 + col];
    float w1 = W[((size_t)ld * 256 + 2 * kp + 1) * 1024 + col];
    Wkm[gid] = packf16(w0, w1);
}

// ---------- chunked input GEMM (split-bf16 MFMA, fp32 out) ----------
__global__ __launch_bounds__(256) void k_gemm_chunk(const unsigned short* __restrict__ Ah,
                                                    const unsigned short* __restrict__ Al,
                                                    const unsigned short* __restrict__ BTh,
                                                    const unsigned short* __restrict__ BTl,
                                                    float* __restrict__ C,
                                                    int t0) {
    __shared__ __align__(16) unsigned short Ahs[128][40];
    __shared__ __align__(16) unsigned short Als[128][40];
    __shared__ __align__(16) unsigned short Bhs[128][40];
    __shared__ __align__(16) unsigned short Bls[128][40];
    const int tid = threadIdx.x;
    const int tm = blockIdx.y * 128;     // gridDim.y = 64  (8192 chunk rows)
    const int tn = blockIdx.x * 128;     // gridDim.x = 8   (1024 gate cols)
    const int lane = tid & 63, w = tid >> 6;
    const int wr = w >> 1, wc = w & 1;
    const int l15 = lane & 15, lk = (lane >> 4) * 8;
    f32x4 acc[4][4];
    for (int i = 0; i < 4; ++i)
        for (int j = 0; j < 4; ++j)
            acc[i][j] = (f32x4){0.f, 0.f, 0.f, 0.f};
    const int srow = tid >> 1, scol = (tid & 1) * 16;
    const int rg = tm + srow;
    const size_t am = (size_t)((rg >> 8) * 1024 + t0 + (rg & 255)) * 512;
    const size_t bm = (size_t)(tn + srow) * 512;
    for (int kt = 0; kt < 512; kt += 32) {
        *reinterpret_cast<uint4*>(&Ahs[srow][scol])     = *reinterpret_cast<const uint4*>(&Ah[am + kt + scol]);
        *reinterpret_cast<uint4*>(&Ahs[srow][scol + 8]) = *reinterpret_cast<const uint4*>(&Ah[am + kt + scol + 8]);
        *reinterpret_cast<uint4*>(&Als[srow][scol])     = *reinterpret_cast<const uint4*>(&Al[am + kt + scol]);
        *reinterpret_cast<uint4*>(&Als[srow][scol + 8]) = *reinterpret_cast<const uint4*>(&Al[am + kt + scol + 8]);
        *reinterpret_cast<uint4*>(&Bhs[srow][scol])     = *reinterpret_cast<const uint4*>(&BTh[bm + kt + scol]);
        *reinterpret_cast<uint4*>(&Bhs[srow][scol + 8]) = *reinterpret_cast<const uint4*>(&BTh[bm + kt + scol + 8]);
        *reinterpret_cast<uint4*>(&Bls[srow][scol])     = *reinterpret_cast<const uint4*>(&BTl[bm + kt + scol]);
        *reinterpret_cast<uint4*>(&Bls[srow][scol + 8]) = *reinterpret_cast<const uint4*>(&BTl[bm + kt + scol + 8]);
        __syncthreads();
        bf16x8 afh[4], afl[4], bfh[4], bfl[4];
        for (int m = 0; m < 4; ++m) {
            afh[m] = *reinterpret_cast<const bf16x8*>(&Ahs[wr * 64 + m * 16 + l15][lk]);
            afl[m] = *reinterpret_cast<const bf16x8*>(&Als[wr * 64 + m * 16 + l15][lk]);
        }
        for (int n = 0; n < 4; ++n) {
            bfh[n] = *reinterpret_cast<const bf16x8*>(&Bhs[wc * 64 + n * 16 + l15][lk]);
            bfl[n] = *reinterpret_cast<const bf16x8*>(&Bls[wc * 64 + n * 16 + l15][lk]);
        }
        for (int m = 0; m < 4; ++m)
            for (int n = 0; n < 4; ++n) {
                acc[m][n] = __builtin_amdgcn_mfma_f32_16x16x32_bf16(afh[m], bfh[n], acc[m][n], 0, 0, 0);
                acc[m][n] = __builtin_amdgcn_mfma_f32_16x16x32_bf16(afl[m], bfh[n], acc[m][n], 0, 0, 0);
                acc[m][n] = __builtin_amdgcn_mfma_f32_16x16x32_bf16(afh[m], bfl[n], acc[m][n], 0, 0, 0);
            }
        __syncthreads();
    }
    const int rbase = tm + wr * 64 + (lane >> 4) * 4;
    const int cbase = tn + wc * 64 + l15;
    for (int m = 0; m < 4; ++m)
        for (int n = 0; n < 4; ++n)
            for (int r = 0; r < 4; ++r) {
                int row = rbase + m * 16 + r;
                int col = cbase + n * 16;
                C[(size_t)row * 1024 + col] = acc[m][n][r];
            }
}

// ---------- LSTM scan: one block per (dir,batch); balanced on-chip weight split ----------
// 64 blocks x 512 threads. Thread t owns cols c0=t and c1=512+t.
//   c0 k=0..127  : REGISTERS wr2[32] (64 VGPR)           -- fits the 128-VGPR cap
//   c0 k=128..255: streamed dwordx2 (identical addrs every step -> L2-hit)
//   c1 k=0..127  : streamed dwordx2
//   c1 k=128..255: LDS Wl2 [s4][col][4], lane-consecutive b128 reads (conflict-free)
// h as fp16 in LDS; per-step reads are wave-uniform (broadcast). 2 barriers/step.
// No cross-block communication (round-5 lesson). Designed for <=128 VGPR (round-6/7 lesson).
__global__ __launch_bounds__(512, 1) void k_scan4(const uint32_t* __restrict__ Wkm,  // [ld][64][1024] uint2
                                                  const float* __restrict__ bias,
                                                  const float* __restrict__ xgA,    // fwd [32][256][1024]
                                                  const float* __restrict__ xgB,    // bwd [32][256][1024]
                                                  float* __restrict__ hout,
                                                  float* __restrict__ hstate,       // [64][256]
                                                  float* __restrict__ cstate,       // [64][256]
                                                  int layer, int chunk) {
    const int g = blockIdx.x;                   // 0..63
    const int d = g >> 5, b = g & 31;
    const int tid = threadIdx.x;                // 0..511
    const int ld = layer * 2 + d;

    __shared__ __align__(16) uint32_t Wl2[16 * 512 * 4];   // 128 KB: [s4][col-512][j]
    __shared__ __align__(16) float gbuf[GATES];            // 4 KB
    __shared__ __align__(16) unsigned short hh_u16[HID];   // h as fp16, 512 B

    const uint2* Wld2 = reinterpret_cast<const uint2*>(Wkm) + (size_t)ld * 65536;

    // ---- stage LDS: cols 512..1023, kq 32..63 (global coalesced dwordx2) ----
    for (int kq = 0; kq < 32; ++kq) {
        uint2 v = Wld2[(size_t)(32 + kq) * 1024 + 512 + tid];
        int s4 = kq >> 1, jj = (kq & 1) * 2;
        Wl2[(s4 * 512 + tid) * 4 + jj]     = v.x;
        Wl2[(s4 * 512 + tid) * 4 + jj + 1] = v.y;
    }
    // ---- stage register cols: col=tid, kq 0..31 (64 VGPR) ----
    uint2 wr2[32];
    #pragma unroll
    for (int kq = 0; kq < 32; ++kq)
        wr2[kq] = Wld2[(size_t)kq * 1024 + tid];

    const float b0 = bias[(size_t)ld * 1024 + tid];
    const float b1 = bias[(size_t)ld * 1024 + 512 + tid];

    float creg = 0.f, hreg = 0.f;
    if (tid < HID) {
        if (chunk != 0) {
            hreg = hstate[(size_t)g * 256 + tid];
            creg = cstate[(size_t)g * 256 + tid];
        }
        hh_u16[tid] = f16b(hreg);
    }
    __syncthreads();

    const float* xbase = (d ? xgB : xgA) + (size_t)b * TCH * 1024;
    const uint2* st0 = Wld2 + tid;              // col c0 stream (kq 32..63)
    const uint2* st1 = Wld2 + 512 + tid;        // col c1 stream (kq 0..31)
    const uint4* hh4 = reinterpret_cast<const uint4*>(hh_u16);
    const uint4* Wl2u4 = reinterpret_cast<const uint4*>(Wl2);

    const int tl0 = d ? (TCH - 1) : 0, tstep = d ? -1 : 1;
    float xg0 = xbase[(size_t)tl0 * 1024 + tid];
    float xg1 = xbase[(size_t)tl0 * 1024 + 512 + tid];

    for (int sl = 0; sl < TCH; ++sl) {
        // prefetch next step's xg (independent of h)
        float xg0n = xg0, xg1n = xg1;
        if (sl + 1 < TCH) {
            size_t r = (size_t)(tl0 + tstep * (sl + 1)) * 1024;
            xg0n = xbase[r + tid];
            xg1n = xbase[r + 512 + tid];
        }

        float a0 = 0.f, a1 = 0.f;
        // group A: kpairs 0..63 -- c0 from regs, c1 streamed
        #pragma unroll 4
        for (int s = 0; s < 16; ++s) {
            uint4 hv = hh4[s];
            uint2 u = st1[(size_t)(2 * s) * 1024];
            uint2 v = st1[(size_t)(2 * s + 1) * 1024];
            uint2 p = wr2[2 * s], q = wr2[2 * s + 1];
            a0 = FDOT2(u2h(p.x), u2h(hv.x), a0);
            a1 = FDOT2(u2h(u.x), u2h(hv.x), a1);
            a0 = FDOT2(u2h(p.y), u2h(hv.y), a0);
            a1 = FDOT2(u2h(u.y), u2h(hv.y), a1);
            a0 = FDOT2(u2h(q.x), u2h(hv.z), a0);
            a1 = FDOT2(u2h(v.x), u2h(hv.z), a1);
            a0 = FDOT2(u2h(q.y), u2h(hv.w), a0);
            a1 = FDOT2(u2h(v.y), u2h(hv.w), a1);
        }
        // group B: kpairs 64..127 -- c0 streamed, c1 from LDS
        #pragma unroll 4
        for (int s = 0; s < 16; ++s) {
            uint4 hv = hh4[16 + s];
            uint2 u = st0[(size_t)(32 + 2 * s) * 1024];
            uint2 v = st0[(size_t)(33 + 2 * s) * 1024];
            uint4 wv = Wl2u4[s * 512 + tid];
            a0 = FDOT2(u2h(u.x), u2h(hv.x), a0);
            a1 = FDOT2(u2h(wv.x), u2h(hv.x), a1);
            a0 = FDOT2(u2h(u.y), u2h(hv.y), a0);
            a1 = FDOT2(u2h(wv.y), u2h(hv.y), a1);
            a0 = FDOT2(u2h(v.x), u2h(hv.z), a0);
            a1 = FDOT2(u2h(wv.z), u2h(hv.z), a1);
            a0 = FDOT2(u2h(v.y), u2h(hv.w), a0);
            a1 = FDOT2(u2h(wv.w), u2h(hv.w), a1);
        }

        float g0 = a0 + b0 + xg0;
        float g1 = a1 + b1 + xg1;
        float s0 = 1.f / (1.f + expf(-g0));                           // c0: i/f -> sigmoid
        float s1 = (tid < 256) ? tanhf(g1) : 1.f / (1.f + expf(-g1)); // c1: g -> tanh, o -> sigmoid
        gbuf[tid] = s0;
        gbuf[512 + tid] = s1;
        __syncthreads();

        if (tid < 256) {
            float iv = gbuf[tid], fv = gbuf[256 + tid];
            float gv = gbuf[512 + tid], ov = gbuf[768 + tid];
            creg = fv * creg + iv * gv;
            hreg = ov * tanhf(creg);
            const int sgl = chunk * TCH + sl;
            const int tg = d ? (FRAMES - 1 - sgl) : sgl;
            hout[((size_t)(d * BATCH + b) * FRAMES + tg) * HID + tid] = hreg;
            hh_u16[tid] = f16b(hreg);
        }
        __syncthreads();
        xg0 = xg0n; xg1 = xg1n;
    }
    if (tid < 256) {
        hstate[(size_t)g * 256 + tid] = hreg;
        cstate[(size_t)g * 256 + tid] = creg;
    }
}

// ---------- dropout(0.5) + ReLU + concat, JAX partitionable threefry ----------
__global__ __launch_bounds__(256) void k_dropout(const float* __restrict__ h,
                                                 unsigned short* __restrict__ xh,  // may be null
                                                 unsigned short* __restrict__ xl,  // may be null
                                                 float* __restrict__ xf,           // may be null
                                                 uint32_t fk0, uint32_t fk1) {
    uint32_t i = blockIdx.x * 256u + threadIdx.x;    // grid 65536 -> NMASK threads
    uint32_t o0, o1;
    tf2x32(fk0, fk1, 0u, i, o0, o1);
    uint32_t bits = o0 ^ o1;
    uint32_t f = i & 511u;
    uint32_t t = (i >> 9) & 1023u;
    uint32_t b = i >> 19;                            // 0..31
    uint32_t dv = f >> 8, n = f & 255u;
    float v = h[(((size_t)dv * BATCH + b) * FRAMES + t) * HID + n];
    float o = (((bits >> 31) == 0u) && v > 0.f) ? 2.f * v : 0.f;
    if (xh != nullptr) {
        unsigned short hb_ = f2bf(o);
        xh[i] = hb_;
        xl[i] = f2bf(o - b2f(hb_));
    }
    if (xf != nullptr) xf[i] = o;
}

// ---------- output projection: out[32768][29] = Xf[32768][512] @ Wout + bout ----------
__global__ __launch_bounds__(256) void k_out(const float* __restrict__ xf,
                                             const float* __restrict__ Wout,
                                             const float* __restrict__ bout,
                                             float* __restrict__ out) {
    __shared__ __align__(16) float Xs[64][68];
    const int tid = threadIdx.x;
    const int r = tid & 63, cg = tid >> 6;           // 4 col-groups of 8 (last has 5)
    const int row0 = blockIdx.x * 64;
    float acc[8] = {0.f, 0.f, 0.f, 0.f, 0.f, 0.f, 0.f, 0.f};
    for (int kc = 0; kc < 512; kc += 64) {
        int sr = tid >> 2, sc = (tid & 3) * 16;
        const float* src = xf + (size_t)(row0 + sr) * 512 + kc + sc;
        *reinterpret_cast<float4*>(&Xs[sr][sc])      = *reinterpret_cast<const float4*>(src);
        *reinterpret_cast<float4*>(&Xs[sr][sc + 4])  = *reinterpret_cast<const float4*>(src + 4);
        *reinterpret_cast<float4*>(&Xs[sr][sc + 8])  = *reinterpret_cast<const float4*>(src + 8);
        *reinterpret_cast<float4*>(&Xs[sr][sc + 12]) = *reinterpret_cast<const float4*>(src + 12);
        __syncthreads();
        for (int k = 0; k < 64; ++k) {
            float xv = Xs[r][k];
            const float* wr = Wout + (size_t)(kc + k) * NCLS + cg * 8;
            #pragma unroll
            for (int cc = 0; cc < 8; ++cc)
                if (cg * 8 + cc < NCLS) acc[cc] = fmaf(xv, wr[cc], acc[cc]);
        }
        __syncthreads();
    }
    for (int cc = 0; cc < 8; ++cc) {
        int col = cg * 8 + cc;
        if (col < NCLS) out[(size_t)(row0 + r) * NCLS + col] = acc[cc] + bout[col];
    }
}

// ---------- launch ----------
extern "C" void kernel_launch(void* const* d_in, const int* in_sizes, int n_in,
                              void* d_out, int out_size, void* d_ws, size_t ws_size,
                              hipStream_t stream) {
    const float* sig  = (const float*)d_in[0];
    const float* Wih  = (const float*)d_in[1];
    const float* Whh  = (const float*)d_in[2];
    const float* bias = (const float*)d_in[3];
    const float* Wout = (const float*)d_in[4];
    const float* bout = (const float*)d_in[5];
    float* out = (float*)d_out;

    char* ws = (char*)d_ws;
    size_t off = 0;
    auto alloc = [&](size_t bytes) -> void* {
        void* p = ws + off;
        off += (bytes + 255) & ~(size_t)255;
        return p;
    };
    float* psum           = (float*)alloc(1024 * 4);
    float* psq            = (float*)alloc(1024 * 4);
    float* mu             = (float*)alloc(32 * 4);
    float* rstd           = (float*)alloc(32 * 4);
    unsigned short* WThi  = (unsigned short*)alloc((size_t)6 * 1024 * 512 * 2);     // 6.3 MB
    unsigned short* WTlo  = (unsigned short*)alloc((size_t)6 * 1024 * 512 * 2);     // 6.3 MB
    uint32_t* Wkm         = (uint32_t*)alloc((size_t)6 * 128 * 1024 * 4);           // 3.1 MB
    unsigned short* xhi   = (unsigned short*)alloc((size_t)MROWS * 512 * 2);        // 33.5 MB
    unsigned short* xlo   = (unsigned short*)alloc((size_t)MROWS * 512 * 2);        // 33.5 MB
    float* xgA            = (float*)alloc((size_t)BATCH * TCH * 1024 * 4);          // 33.5 MB
    float* xgB            = (float*)alloc((size_t)BATCH * TCH * 1024 * 4);          // 33.5 MB
    float* hb             = (float*)alloc((size_t)2 * BATCH * FRAMES * HID * 4);    // 67 MB
    float* hstate         = (float*)alloc((size_t)64 * HID * 4);
    float* cstate         = (float*)alloc((size_t)64 * HID * 4);
    // Total ~218 MB (round-4/6/7 proven layout).
    float* xf32           = (float*)xhi;   // layer-2 fp32 activations overlay dead xhi/xlo

    k_stats1<<<1024, 256, 0, stream>>>(sig, psum, psq);
    k_stats2<<<1, 1024, 0, stream>>>(psum, psq, mu, rstd);
    k_norm<<<16384, 256, 0, stream>>>(sig, mu, rstd, xhi, xlo);
    k_wih_t<<<12288, 256, 0, stream>>>(Wih, WThi, WTlo);
    k_wkm<<<3072, 256, 0, stream>>>(Whh, Wkm);

    for (int l = 0; l < 3; ++l) {
        const unsigned short* Bh0 = WThi + (size_t)(l * 2 + 0) * 1024 * 512;
        const unsigned short* Bl0 = WTlo + (size_t)(l * 2 + 0) * 1024 * 512;
        const unsigned short* Bh1 = WThi + (size_t)(l * 2 + 1) * 1024 * 512;
        const unsigned short* Bl1 = WTlo + (size_t)(l * 2 + 1) * 1024 * 512;
        for (int c = 0; c < NCHUNK; ++c) {
            dim3 gg(8, 64);
            int t0f = c * TCH;
            int t0b = (NCHUNK - 1 - c) * TCH;
            k_gemm_chunk<<<gg, 256, 0, stream>>>(xhi, xlo, Bh0, Bl0, xgA, t0f);
            k_gemm_chunk<<<gg, 256, 0, stream>>>(xhi, xlo, Bh1, Bl1, xgB, t0b);
            k_scan4<<<64, 512, 0, stream>>>(Wkm, bias, xgA, xgB, hb, hstate, cstate, l, c);
        }
        uint32_t fk0, fk1;
        tf2x32(0u, 42u, 0u, (uint32_t)l, fk0, fk1);
        if (l < 2)
            k_dropout<<<65536, 256, 0, stream>>>(hb, xhi, xlo, nullptr, fk0, fk1);
        else
            k_dropout<<<65536, 256, 0, stream>>>(hb, nullptr, nullptr, xf32, fk0, fk1);
    }
    k_out<<<512, 256, 0, stream>>>(xf32, Wout, bout, out);
}

// Round 9
// 7562.935 us; speedup vs baseline: 12.4682x; 3.2866x over previous
//
#include <hip/hip_runtime.h>
#include <cstdint>
#include <cstddef>

// ---------- small helpers ----------
typedef __bf16 bf16x8 __attribute__((ext_vector_type(8)));
typedef float  f32x4  __attribute__((ext_vector_type(4)));
typedef _Float16 h2 __attribute__((ext_vector_type(2)));

__device__ __forceinline__ float b2f(unsigned short u) {
    union { uint32_t i; float f; } x; x.i = ((uint32_t)u) << 16; return x.f;
}
__device__ __forceinline__ unsigned short f2bf(float f) {
    uint32_t u = __float_as_uint(f);
    uint32_t r = (u + 0x7FFFu + ((u >> 16) & 1u)) >> 16;   // RNE, no NaN in data
    return (unsigned short)r;
}
__device__ __forceinline__ uint32_t packf16(float a, float b) {
    union { _Float16 h[2]; uint32_t u; } x;
    x.h[0] = (_Float16)a; x.h[1] = (_Float16)b; return x.u;
}
__device__ __forceinline__ h2 u2h(uint32_t u) {
    union { uint32_t u; h2 v; } x; x.u = u; return x.v;
}
__device__ __forceinline__ unsigned short f16b(float f) {
    union { _Float16 h; unsigned short u; } x; x.h = (_Float16)f; return x.u;
}

#if __has_builtin(__builtin_amdgcn_fdot2)
#define FDOT2(w, hh, acc) __builtin_amdgcn_fdot2((w), (hh), (acc), false)
#else
__device__ __forceinline__ float fdot2_sw(h2 a, h2 b, float c) {
    return c + (float)a[0] * (float)b[0] + (float)a[1] * (float)b[1];
}
#define FDOT2(w, hh, acc) fdot2_sw((w), (hh), (acc))
#endif

// JAX threefry2x32 (20 rounds), usable host+device
__host__ __device__ inline void tf2x32(uint32_t k0, uint32_t k1,
                                       uint32_t x0, uint32_t x1,
                                       uint32_t& o0, uint32_t& o1) {
    uint32_t ks2 = k0 ^ k1 ^ 0x1BD11BDAu;
#define TF_ROT(x,n) (((x) << (n)) | ((x) >> (32 - (n))))
#define TF_RND(r) { x0 += x1; x1 = TF_ROT(x1, r); x1 ^= x0; }
    x0 += k0; x1 += k1;
    TF_RND(13) TF_RND(15) TF_RND(26) TF_RND(6)
    x0 += k1; x1 += ks2 + 1u;
    TF_RND(17) TF_RND(29) TF_RND(16) TF_RND(24)
    x0 += ks2; x1 += k0 + 2u;
    TF_RND(13) TF_RND(15) TF_RND(26) TF_RND(6)
    x0 += k0; x1 += k1 + 3u;
    TF_RND(17) TF_RND(29) TF_RND(16) TF_RND(24)
    x0 += k1; x1 += ks2 + 4u;
    TF_RND(13) TF_RND(15) TF_RND(26) TF_RND(6)
    x0 += ks2; x1 += k0 + 5u;
    o0 = x0; o1 = x1;
#undef TF_RND
#undef TF_ROT
}

// ---------- constants ----------
#define BATCH 32
#define TSAMP 524288
#define FRAMES 1024
#define HID 256
#define GATES 1024            // 4*HID
#define MROWS 32768           // BATCH*FRAMES
#define NCLS 29
#define NMASK 16777216u       // 32*1024*512
#define TCH 256               // time chunk
#define NCHUNK 4

// ---------- stats: per-batch mean / 1/(std+eps) ----------
__global__ __launch_bounds__(256) void k_stats1(const float* __restrict__ sig,
                                                float* __restrict__ psum,
                                                float* __restrict__ psq) {
    int blk = blockIdx.x;               // 1024 blocks, 32 per batch
    int tid = threadIdx.x;
    size_t base = (size_t)blk * 16384;
    float s = 0.f, q = 0.f;
    for (int i = 0; i < 16; ++i) {
        float4 v = *reinterpret_cast<const float4*>(sig + base + ((size_t)i * 256 + tid) * 4);
        s += v.x + v.y + v.z + v.w;
        q += v.x * v.x + v.y * v.y + v.z * v.z + v.w * v.w;
    }
    __shared__ float ls[4], lq[4];
    int w = tid >> 6, lane = tid & 63;
    for (int m = 32; m; m >>= 1) { s += __shfl_down(s, m); q += __shfl_down(q, m); }
    if (lane == 0) { ls[w] = s; lq[w] = q; }
    __syncthreads();
    if (tid == 0) {
        psum[blk] = ls[0] + ls[1] + ls[2] + ls[3];
        psq[blk]  = lq[0] + lq[1] + lq[2] + lq[3];
    }
}

__global__ __launch_bounds__(1024) void k_stats2(const float* __restrict__ psum,
                                                 const float* __restrict__ psq,
                                                 float* __restrict__ mu,
                                                 float* __restrict__ rstd) {
    int tid = threadIdx.x;              // 1024 = 32 batches * 32 chunks
    float s = psum[tid], q = psq[tid];
    for (int m = 16; m; m >>= 1) { s += __shfl_down(s, m); q += __shfl_down(q, m); }
    if ((tid & 31) == 0) {
        int b = tid >> 5;
        float m_ = s * (1.f / (float)TSAMP);
        float v  = q * (1.f / (float)TSAMP) - m_ * m_;
        float sd = sqrtf(fmaxf(v, 0.f));
        mu[b] = m_;
        rstd[b] = 1.f / (sd + 1e-8f);
    }
}

// ---------- normalize + frame -> bf16 hi/lo pair [32768][512] ----------
__global__ __launch_bounds__(256) void k_norm(const float* __restrict__ sig,
                                              const float* __restrict__ mu,
                                              const float* __restrict__ rstd,
                                              unsigned short* __restrict__ xh,
                                              unsigned short* __restrict__ xl) {
    size_t gid = (size_t)blockIdx.x * 256 + threadIdx.x;   // 4194304 threads, 4 elems each
    int b = (int)(gid >> 17);
    float m = mu[b], r = rstd[b];
    float4 v = *reinterpret_cast<const float4*>(sig + gid * 4);
    float f0 = (v.x - m) * r, f1 = (v.y - m) * r, f2 = (v.z - m) * r, f3 = (v.w - m) * r;
    ushort4 oh, ol;
    oh.x = f2bf(f0); ol.x = f2bf(f0 - b2f(oh.x));
    oh.y = f2bf(f1); ol.y = f2bf(f1 - b2f(oh.y));
    oh.z = f2bf(f2); ol.z = f2bf(f2 - b2f(oh.z));
    oh.w = f2bf(f3); ol.w = f2bf(f3 - b2f(oh.w));
    *reinterpret_cast<ushort4*>(xh + gid * 4) = oh;
    *reinterpret_cast<ushort4*>(xl + gid * 4) = ol;
}

// ---------- weight prep: Wih transpose + hi/lo split ----------
__global__ __launch_bounds__(256) void k_wih_t(const float* __restrict__ Wih,
                                               unsigned short* __restrict__ WTh,
                                               unsigned short* __restrict__ WTl) {
    size_t gid = (size_t)blockIdx.x * 256 + threadIdx.x;   // 3145728
    int k = (int)(gid & 511);
    int n = (int)((gid >> 9) & 1023);
    int ld = (int)(gid >> 19);
    float w = Wih[((size_t)ld * 512 + k) * 1024 + n];
    unsigned short h = f2bf(w);
    WTh[gid] = h;
    WTl[gid] = f2bf(w - b2f(h));
}

// ---------- weight prep: Whh -> packed fp16, uint4 layout [ld][kg=32][col=1024] ----------
// uint4 component j holds kpair (k = 8*kg + 2j, 8*kg + 2j + 1) of column col.
__global__ __launch_bounds__(256) void k_wkm4(const float* __restrict__ W,
                                              uint4* __restrict__ Wk4) {
    uint32_t gid = blockIdx.x * 256u + threadIdx.x;        // 196608
    int col = (int)(gid & 1023);
    int kg  = (int)((gid >> 10) & 31);
    int ld  = (int)(gid >> 15);
    const float* base = W + (size_t)ld * 256 * 1024 + col;
    uint4 v;
    v.x = packf16(base[(size_t)(8 * kg + 0) * 1024], base[(size_t)(8 * kg + 1) * 1024]);
    v.y = packf16(base[(size_t)(8 * kg + 2) * 1024], base[(size_t)(8 * kg + 3) * 1024]);
    v.z = packf16(base[(size_t)(8 * kg + 4) * 1024], base[(size_t)(8 * kg + 5) * 1024]);
    v.w = packf16(base[(size_t)(8 * kg + 6) * 1024], base[(size_t)(8 * kg + 7) * 1024]);
    Wk4[gid] = v;
}

// ---------- chunked input GEMM (split-bf16 MFMA, fp32 out) ----------
__global__ __launch_bounds__(256) void k_gemm_chunk(const unsigned short* __restrict__ Ah,
                                                    const unsigned short* __restrict__ Al,
                                                    const unsigned short* __restrict__ BTh,
                                                    const unsigned short* __restrict__ BTl,
                                                    float* __restrict__ C,
                                                    int t0) {
    __shared__ __align__(16) unsigned short Ahs[128][40];
    __shared__ __align__(16) unsigned short Als[128][40];
    __shared__ __align__(16) unsigned short Bhs[128][40];
    __shared__ __align__(16) unsigned short Bls[128][40];
    const int tid = threadIdx.x;
    const int tm = blockIdx.y * 128;     // gridDim.y = 64  (8192 chunk rows)
    const int tn = blockIdx.x * 128;     // gridDim.x = 8   (1024 gate cols)
    const int lane = tid & 63, w = tid >> 6;
    const int wr = w >> 1, wc = w & 1;
    const int l15 = lane & 15, lk = (lane >> 4) * 8;
    f32x4 acc[4][4];
    for (int i = 0; i < 4; ++i)
        for (int j = 0; j < 4; ++j)
            acc[i][j] = (f32x4){0.f, 0.f, 0.f, 0.f};
    const int srow = tid >> 1, scol = (tid & 1) * 16;
    const int rg = tm + srow;
    const size_t am = (size_t)((rg >> 8) * 1024 + t0 + (rg & 255)) * 512;
    const size_t bm = (size_t)(tn + srow) * 512;
    for (int kt = 0; kt < 512; kt += 32) {
        *reinterpret_cast<uint4*>(&Ahs[srow][scol])     = *reinterpret_cast<const uint4*>(&Ah[am + kt + scol]);
        *reinterpret_cast<uint4*>(&Ahs[srow][scol + 8]) = *reinterpret_cast<const uint4*>(&Ah[am + kt + scol + 8]);
        *reinterpret_cast<uint4*>(&Als[srow][scol])     = *reinterpret_cast<const uint4*>(&Al[am + kt + scol]);
        *reinterpret_cast<uint4*>(&Als[srow][scol + 8]) = *reinterpret_cast<const uint4*>(&Al[am + kt + scol + 8]);
        *reinterpret_cast<uint4*>(&Bhs[srow][scol])     = *reinterpret_cast<const uint4*>(&BTh[bm + kt + scol]);
        *reinterpret_cast<uint4*>(&Bhs[srow][scol + 8]) = *reinterpret_cast<const uint4*>(&BTh[bm + kt + scol + 8]);
        *reinterpret_cast<uint4*>(&Bls[srow][scol])     = *reinterpret_cast<const uint4*>(&BTl[bm + kt + scol]);
        *reinterpret_cast<uint4*>(&Bls[srow][scol + 8]) = *reinterpret_cast<const uint4*>(&BTl[bm + kt + scol + 8]);
        __syncthreads();
        bf16x8 afh[4], afl[4], bfh[4], bfl[4];
        for (int m = 0; m < 4; ++m) {
            afh[m] = *reinterpret_cast<const bf16x8*>(&Ahs[wr * 64 + m * 16 + l15][lk]);
            afl[m] = *reinterpret_cast<const bf16x8*>(&Als[wr * 64 + m * 16 + l15][lk]);
        }
        for (int n = 0; n < 4; ++n) {
            bfh[n] = *reinterpret_cast<const bf16x8*>(&Bhs[wc * 64 + n * 16 + l15][lk]);
            bfl[n] = *reinterpret_cast<const bf16x8*>(&Bls[wc * 64 + n * 16 + l15][lk]);
        }
        for (int m = 0; m < 4; ++m)
            for (int n = 0; n < 4; ++n) {
                acc[m][n] = __builtin_amdgcn_mfma_f32_16x16x32_bf16(afh[m], bfh[n], acc[m][n], 0, 0, 0);
                acc[m][n] = __builtin_amdgcn_mfma_f32_16x16x32_bf16(afl[m], bfh[n], acc[m][n], 0, 0, 0);
                acc[m][n] = __builtin_amdgcn_mfma_f32_16x16x32_bf16(afh[m], bfl[n], acc[m][n], 0, 0, 0);
            }
        __syncthreads();
    }
    const int rbase = tm + wr * 64 + (lane >> 4) * 4;
    const int cbase = tn + wc * 64 + l15;
    for (int m = 0; m < 4; ++m)
        for (int n = 0; n < 4; ++n)
            for (int r = 0; r < 4; ++r) {
                int row = rbase + m * 16 + r;
                int col = cbase + n * 16;
                C[(size_t)row * 1024 + col] = acc[m][n][r];
            }
}

// ---------- LSTM scan: one block per (dir,batch); 1024 threads, 16 waves ----------
// Thread t owns gate column t. Weights (fp16 pairs, uint4 kg-groups of 8 k):
//   kg 0..15  (k 0..127)  : REGISTERS wreg[16] (64 VGPR)
//   kg 16..23 (k128..191) : LDS Wl4[kg][col], lane-consecutive b128 (conflict-free)
//   kg 24..31 (k192..255) : streamed dwordx4, 1 KB/wave coalesced (L2-resident)
// h as fp16 in LDS (wave-uniform b128 broadcast reads). 4 accumulators.
// hout store issued AFTER the step's last barrier (ack drains under next dot).
// 16 waves = 4/SIMD doubles latency-hiding vs round 8 (the measured stall source).
__global__ __launch_bounds__(1024, 4) void k_scan5(const uint4* __restrict__ Wk4,  // [ld][32][1024]
                                                   const float* __restrict__ bias,
                                                   const float* __restrict__ xgA,  // fwd [32][256][1024]
                                                   const float* __restrict__ xgB,  // bwd [32][256][1024]
                                                   float* __restrict__ hout,
                                                   float* __restrict__ hstate,     // [64][256]
                                                   float* __restrict__ cstate,     // [64][256]
                                                   int layer, int chunk) {
    const int g = blockIdx.x;                   // 0..63
    const int d = g >> 5, b = g & 31;
    const int tid = threadIdx.x;                // 0..1023 == gate column
    const int ld = layer * 2 + d;

    __shared__ __align__(16) uint4 Wl4[8 * 1024];          // 128 KB: [kg-16][col]
    __shared__ __align__(16) float gbuf[GATES];            // 4 KB
    __shared__ __align__(16) unsigned short hh_u16[HID];   // h as fp16, 512 B

    const uint4* W = Wk4 + (size_t)ld * 32 * 1024;

    // ---- stage LDS kg 16..23 (coalesced both sides) ----
    #pragma unroll
    for (int kg = 0; kg < 8; ++kg)
        Wl4[kg * 1024 + tid] = W[(size_t)(16 + kg) * 1024 + tid];
    // ---- stage register kg 0..15 (64 VGPR) ----
    uint4 wreg[16];
    #pragma unroll
    for (int kg = 0; kg < 16; ++kg)
        wreg[kg] = W[(size_t)kg * 1024 + tid];

    const float bcol = bias[(size_t)ld * 1024 + tid];
    const int gate = tid >> 8;                  // wave-uniform (4 waves per gate)

    float creg = 0.f, hreg = 0.f;
    if (tid < HID) {
        if (chunk != 0) {
            hreg = hstate[(size_t)g * 256 + tid];
            creg = cstate[(size_t)g * 256 + tid];
        }
        hh_u16[tid] = f16b(hreg);
    }
    __syncthreads();

    const float* xbase = (d ? xgB : xgA) + (size_t)b * TCH * 1024;
    const uint4* wst = W + (size_t)24 * 1024 + tid;        // streamed kg 24..31
    const uint4* hh4 = reinterpret_cast<const uint4*>(hh_u16);

    const int tl0 = d ? (TCH - 1) : 0, tstep = d ? -1 : 1;
    float xg = xbase[(size_t)tl0 * 1024 + tid];
    float hprev = 0.f;                                     // pending hout value
    int   tgprev = -1;

    for (int sl = 0; sl < TCH; ++sl) {
        float xgn = xg;
        if (sl + 1 < TCH)
            xgn = xbase[(size_t)(tl0 + tstep * (sl + 1)) * 1024 + tid];

        float a0 = 0.f, a1 = 0.f, a2 = 0.f, a3 = 0.f;
        // registers: kg 0..15
        #pragma unroll
        for (int kg = 0; kg < 16; ++kg) {
            uint4 hv = hh4[kg];
            uint4 wv = wreg[kg];
            a0 = FDOT2(u2h(wv.x), u2h(hv.x), a0);
            a1 = FDOT2(u2h(wv.y), u2h(hv.y), a1);
            a2 = FDOT2(u2h(wv.z), u2h(hv.z), a2);
            a3 = FDOT2(u2h(wv.w), u2h(hv.w), a3);
        }
        // LDS: kg 16..23
        #pragma unroll
        for (int kg = 0; kg < 8; ++kg) {
            uint4 hv = hh4[16 + kg];
            uint4 wv = Wl4[kg * 1024 + tid];
            a0 = FDOT2(u2h(wv.x), u2h(hv.x), a0);
            a1 = FDOT2(u2h(wv.y), u2h(hv.y), a1);
            a2 = FDOT2(u2h(wv.z), u2h(hv.z), a2);
            a3 = FDOT2(u2h(wv.w), u2h(hv.w), a3);
        }
        // stream: kg 24..31
        #pragma unroll
        for (int kg = 0; kg < 8; ++kg) {
            uint4 hv = hh4[24 + kg];
            uint4 wv = wst[(size_t)kg * 1024];
            a0 = FDOT2(u2h(wv.x), u2h(hv.x), a0);
            a1 = FDOT2(u2h(wv.y), u2h(hv.y), a1);
            a2 = FDOT2(u2h(wv.z), u2h(hv.z), a2);
            a3 = FDOT2(u2h(wv.w), u2h(hv.w), a3);
        }

        float gv = (a0 + a1) + (a2 + a3) + bcol + xg;
        gbuf[tid] = (gate == 2) ? tanhf(gv) : 1.f / (1.f + expf(-gv));
        __syncthreads();

        if (tid < HID) {
            float iv = gbuf[tid], fv = gbuf[256 + tid];
            float gg = gbuf[512 + tid], ov = gbuf[768 + tid];
            creg = fv * creg + iv * gg;
            hreg = ov * tanhf(creg);
            hh_u16[tid] = f16b(hreg);
            const int sgl = chunk * TCH + sl;
            tgprev = d ? (FRAMES - 1 - sgl) : sgl;
            hprev = hreg;
        }
        __syncthreads();
        // deferred global store: ack drains under the next dot phase
        if (tid < HID)
            hout[((size_t)(d * BATCH + b) * FRAMES + tgprev) * HID + tid] = hprev;
        xg = xgn;
    }
    if (tid < HID) {
        hstate[(size_t)g * 256 + tid] = hreg;
        cstate[(size_t)g * 256 + tid] = creg;
    }
}

// ---------- dropout(0.5) + ReLU + concat, JAX partitionable threefry ----------
__global__ __launch_bounds__(256) void k_dropout(const float* __restrict__ h,
                                                 unsigned short* __restrict__ xh,  // may be null
                                                 unsigned short* __restrict__ xl,  // may be null
                                                 float* __restrict__ xf,           // may be null
                                                 uint32_t fk0, uint32_t fk1) {
    uint32_t i = blockIdx.x * 256u + threadIdx.x;    // grid 65536 -> NMASK threads
    uint32_t o0, o1;
    tf2x32(fk0, fk1, 0u, i, o0, o1);
    uint32_t bits = o0 ^ o1;
    uint32_t f = i & 511u;
    uint32_t t = (i >> 9) & 1023u;
    uint32_t b = i >> 19;                            // 0..31
    uint32_t dv = f >> 8, n = f & 255u;
    float v = h[(((size_t)dv * BATCH + b) * FRAMES + t) * HID + n];
    float o = (((bits >> 31) == 0u) && v > 0.f) ? 2.f * v : 0.f;
    if (xh != nullptr) {
        unsigned short hb_ = f2bf(o);
        xh[i] = hb_;
        xl[i] = f2bf(o - b2f(hb_));
    }
    if (xf != nullptr) xf[i] = o;
}

// ---------- output projection: out[32768][29] = Xf[32768][512] @ Wout + bout ----------
__global__ __launch_bounds__(256) void k_out(const float* __restrict__ xf,
                                             const float* __restrict__ Wout,
                                             const float* __restrict__ bout,
                                             float* __restrict__ out) {
    __shared__ __align__(16) float Xs[64][68];
    const int tid = threadIdx.x;
    const int r = tid & 63, cg = tid >> 6;           // 4 col-groups of 8 (last has 5)
    const int row0 = blockIdx.x * 64;
    float acc[8] = {0.f, 0.f, 0.f, 0.f, 0.f, 0.f, 0.f, 0.f};
    for (int kc = 0; kc < 512; kc += 64) {
        int sr = tid >> 2, sc = (tid & 3) * 16;
        const float* src = xf + (size_t)(row0 + sr) * 512 + kc + sc;
        *reinterpret_cast<float4*>(&Xs[sr][sc])      = *reinterpret_cast<const float4*>(src);
        *reinterpret_cast<float4*>(&Xs[sr][sc + 4])  = *reinterpret_cast<const float4*>(src + 4);
        *reinterpret_cast<float4*>(&Xs[sr][sc + 8])  = *reinterpret_cast<const float4*>(src + 8);
        *reinterpret_cast<float4*>(&Xs[sr][sc + 12]) = *reinterpret_cast<const float4*>(src + 12);
        __syncthreads();
        for (int k = 0; k < 64; ++k) {
            float xv = Xs[r][k];
            const float* wr = Wout + (size_t)(kc + k) * NCLS + cg * 8;
            #pragma unroll
            for (int cc = 0; cc < 8; ++cc)
                if (cg * 8 + cc < NCLS) acc[cc] = fmaf(xv, wr[cc], acc[cc]);
        }
        __syncthreads();
    }
    for (int cc = 0; cc < 8; ++cc) {
        int col = cg * 8 + cc;
        if (col < NCLS) out[(size_t)(row0 + r) * NCLS + col] = acc[cc] + bout[col];
    }
}

// ---------- launch ----------
extern "C" void kernel_launch(void* const* d_in, const int* in_sizes, int n_in,
                              void* d_out, int out_size, void* d_ws, size_t ws_size,
                              hipStream_t stream) {
    const float* sig  = (const float*)d_in[0];
    const float* Wih  = (const float*)d_in[1];
    const float* Whh  = (const float*)d_in[2];
    const float* bias = (const float*)d_in[3];
    const float* Wout = (const float*)d_in[4];
    const float* bout = (const float*)d_in[5];
    float* out = (float*)d_out;

    char* ws = (char*)d_ws;
    size_t off = 0;
    auto alloc = [&](size_t bytes) -> void* {
        void* p = ws + off;
        off += (bytes + 255) & ~(size_t)255;
        return p;
    };
    float* psum           = (float*)alloc(1024 * 4);
    float* psq            = (float*)alloc(1024 * 4);
    float* mu             = (float*)alloc(32 * 4);
    float* rstd           = (float*)alloc(32 * 4);
    unsigned short* WThi  = (unsigned short*)alloc((size_t)6 * 1024 * 512 * 2);     // 6.3 MB
    unsigned short* WTlo  = (unsigned short*)alloc((size_t)6 * 1024 * 512 * 2);     // 6.3 MB
    uint4* Wk4            = (uint4*)alloc((size_t)6 * 32 * 1024 * 16);              // 3.1 MB
    unsigned short* xhi   = (unsigned short*)alloc((size_t)MROWS * 512 * 2);        // 33.5 MB
    unsigned short* xlo   = (unsigned short*)alloc((size_t)MROWS * 512 * 2);        // 33.5 MB
    float* xgA            = (float*)alloc((size_t)BATCH * TCH * 1024 * 4);          // 33.5 MB
    float* xgB            = (float*)alloc((size_t)BATCH * TCH * 1024 * 4);          // 33.5 MB
    float* hb             = (float*)alloc((size_t)2 * BATCH * FRAMES * HID * 4);    // 67 MB
    float* hstate         = (float*)alloc((size_t)64 * HID * 4);
    float* cstate         = (float*)alloc((size_t)64 * HID * 4);
    // Total ~218 MB (proven layout).
    float* xf32           = (float*)xhi;   // layer-2 fp32 activations overlay dead xhi/xlo

    k_stats1<<<1024, 256, 0, stream>>>(sig, psum, psq);
    k_stats2<<<1, 1024, 0, stream>>>(psum, psq, mu, rstd);
    k_norm<<<16384, 256, 0, stream>>>(sig, mu, rstd, xhi, xlo);
    k_wih_t<<<12288, 256, 0, stream>>>(Wih, WThi, WTlo);
    k_wkm4<<<768, 256, 0, stream>>>(Whh, Wk4);

    for (int l = 0; l < 3; ++l) {
        const unsigned short* Bh0 = WThi + (size_t)(l * 2 + 0) * 1024 * 512;
        const unsigned short* Bl0 = WTlo + (size_t)(l * 2 + 0) * 1024 * 512;
        const unsigned short* Bh1 = WThi + (size_t)(l * 2 + 1) * 1024 * 512;
        const unsigned short* Bl1 = WTlo + (size_t)(l * 2 + 1) * 1024 * 512;
        for (int c = 0; c < NCHUNK; ++c) {
            dim3 gg(8, 64);
            int t0f = c * TCH;
            int t0b = (NCHUNK - 1 - c) * TCH;
            k_gemm_chunk<<<gg, 256, 0, stream>>>(xhi, xlo, Bh0, Bl0, xgA, t0f);
            k_gemm_chunk<<<gg, 256, 0, stream>>>(xhi, xlo, Bh1, Bl1, xgB, t0b);
            k_scan5<<<64, 1024, 0, stream>>>(Wk4, bias, xgA, xgB, hb, hstate, cstate, l, c);
        }
        uint32_t fk0, fk1;
        tf2x32(0u, 42u, 0u, (uint32_t)l, fk0, fk1);
        if (l < 2)
            k_dropout<<<65536, 256, 0, stream>>>(hb, xhi, xlo, nullptr, fk0, fk1);
        else
            k_dropout<<<65536, 256, 0, stream>>>(hb, nullptr, nullptr, xf32, fk0, fk1);
    }
    k_out<<<512, 256, 0, stream>>>(xf32, Wout, bout, out);
}